// Round 13
// baseline (567.016 us; speedup 1.0000x reference)
//
#include <hip/hip_runtime.h>
#include <hip/hip_bf16.h>
#include <stdint.h>

#define NNODES 50000
#define NEDGES 800000
#define NF 128
#define NH 256

typedef __attribute__((ext_vector_type(8))) __bf16 bf16x8;
typedef __attribute__((ext_vector_type(8))) unsigned short u16x8;
typedef __attribute__((ext_vector_type(4))) float f32x4;

__device__ __forceinline__ unsigned short f2bf(float f) {
    union { float f; unsigned int u; } v; v.f = f;
    unsigned int r = v.u + 0x7fffu + ((v.u >> 16) & 1u);
    return (unsigned short)(r >> 16);
}

// packed f32x2 -> bf16x2 (RNE on gfx950; T12/m214 refcheck-proven)
__device__ __forceinline__ unsigned int cvtpk(float lo, float hi) {
    unsigned int r;
    asm volatile("v_cvt_pk_bf16_f32 %0, %1, %2" : "=v"(r) : "v"(lo), "v"(hi));
    return r;
}

__device__ __forceinline__ void gload16(const void* g, void* l) {
    __builtin_amdgcn_global_load_lds(
        (const __attribute__((address_space(1))) void*)g,
        (__attribute__((address_space(3))) void*)l,
        16, 0, 0);
}

// W [K][Nn] f32 row-major -> Wt [Nn][K] bf16
__global__ __launch_bounds__(256) void tcvt_kernel(const float* __restrict__ W,
                                                   unsigned short* __restrict__ Wt, int K, int Nn) {
    int i = blockIdx.x * 256 + threadIdx.x;
    if (i < K * Nn) {
        int k = i / Nn, n = i - k * Nn;
        Wt[n * K + k] = f2bf(W[i]);
    }
}

// W1 [256][256] f32 -> Wtpq [512][128] bf16 : n<256 -> W1a col n; n>=256 -> W1b col n-256
__global__ __launch_bounds__(256) void wpq_kernel(const float* __restrict__ W1,
                                                  unsigned short* __restrict__ Wtpq) {
    int i = blockIdx.x * 256 + threadIdx.x;
    if (i < 512 * 128) {
        int n = i >> 7, k = i & 127;
        float v = (n < 256) ? W1[k * 256 + n] : W1[(128 + k) * 256 + (n - 256)];
        Wtpq[i] = f2bf(v);
    }
}

// ---------------- sort-by-row kernels ----------------
__global__ __launch_bounds__(256) void hist_kernel(const int* __restrict__ row, int* __restrict__ cnt) {
    int e = blockIdx.x * 256 + threadIdx.x;
    if (e < NEDGES) atomicAdd(&cnt[row[e]], 1);
}

__global__ __launch_bounds__(1024) void scan_kernel(const int* __restrict__ cnt, int* __restrict__ base, int n) {
    __shared__ int wsum[16];
    __shared__ int s_carry;
    const int tid = threadIdx.x;
    const int lane = tid & 63;
    const int wv = tid >> 6;
    if (tid == 0) s_carry = 0;
    __syncthreads();
    for (int off = 0; off < n; off += 1024) {
        int v = (off + tid < n) ? cnt[off + tid] : 0;
        int acc = v;
        #pragma unroll
        for (int s = 1; s < 64; s <<= 1) {
            int t = __shfl_up(acc, s);
            if (lane >= s) acc += t;
        }
        if (lane == 63) wsum[wv] = acc;
        __syncthreads();
        if (wv == 0) {
            int x = (lane < 16) ? wsum[lane] : 0;
            #pragma unroll
            for (int s = 1; s < 16; s <<= 1) {
                int t = __shfl_up(x, s);
                if (lane >= s) x += t;
            }
            if (lane < 16) wsum[lane] = x;
        }
        __syncthreads();
        int c = s_carry;
        int wtot = __shfl(acc, 63);
        int woff = wsum[wv] - wtot;
        if (off + tid < n) base[off + tid] = c + woff + acc - v;
        __syncthreads();
        if (tid == 0) s_carry = c + wsum[15];
        __syncthreads();
    }
}

__global__ __launch_bounds__(256) void scatter_kernel(const int* __restrict__ ei,
                                                      const int* __restrict__ base,
                                                      int* __restrict__ cursor,
                                                      unsigned short* __restrict__ ssrc,
                                                      unsigned short* __restrict__ sdst) {
    int e = blockIdx.x * 256 + threadIdx.x;
    if (e < NEDGES) {
        int r = ei[e];
        int c = ei[NEDGES + e];
        int pos = base[r] + atomicAdd(&cursor[r], 1);
        ssrc[pos] = (unsigned short)r;
        sdst[pos] = (unsigned short)c;
    }
}

// ---------------- P/Q precompute ----------------
// P = h@W1a + b1, Q = h@W1b  (both [NNODES][256] bf16). BM=64, K=128, 4 waves.
__global__ __launch_bounds__(256, 2)
void pq_kernel(const float* __restrict__ h,
               const unsigned short* __restrict__ Wtpq,
               const float* __restrict__ b1,
               unsigned short* __restrict__ P,
               unsigned short* __restrict__ Q)
{
    __shared__ __align__(16) unsigned short A_lds[64 * 128];
    const int tid = threadIdx.x;
    const int lane = tid & 63;
    const int w = tid >> 6;
    const int l15 = lane & 15;
    const int g = lane >> 4;
    const int r0 = blockIdx.x * 64;

    float b1r[4];
    #pragma unroll
    for (int n = 0; n < 4; ++n) b1r[n] = b1[w * 64 + n * 16 + l15];

    // reg-stage A (h f32 -> bf16, swizzled chunks)
    #pragma unroll
    for (int i = 0; i < 4; ++i) {
        int idx = i * 256 + tid;
        int row = idx >> 4, cl = idx & 15;
        int nd = r0 + row; if (nd >= NNODES) nd = NNODES - 1;
        const float* sp = h + (size_t)nd * NF + ((cl ^ (row & 7)) * 8);
        float4 va = *(const float4*)sp;
        float4 vb = *(const float4*)(sp + 4);
        u16x8 mv;
        mv[0] = f2bf(va.x); mv[1] = f2bf(va.y); mv[2] = f2bf(va.z); mv[3] = f2bf(va.w);
        mv[4] = f2bf(vb.x); mv[5] = f2bf(vb.y); mv[6] = f2bf(vb.z); mv[7] = f2bf(vb.w);
        *(u16x8*)(void*)&A_lds[row * 128 + cl * 8] = mv;
    }
    __syncthreads();

    #pragma unroll
    for (int p = 0; p < 2; ++p) {
        bf16x8 Bf[4][4];
        #pragma unroll
        for (int n = 0; n < 4; ++n) {
            int cn = w * 64 + n * 16 + l15;
            #pragma unroll
            for (int ks = 0; ks < 4; ++ks)
                Bf[n][ks] = *(const bf16x8*)(const void*)&Wtpq[(size_t)(p * 256 + cn) * 128 + ks * 32 + 8 * g];
        }
        f32x4 acc[4][4] = {};
        #pragma unroll
        for (int ks = 0; ks < 4; ++ks) {
            bf16x8 af[4];
            #pragma unroll
            for (int m = 0; m < 4; ++m) {
                int r = m * 16 + l15;
                af[m] = *(const bf16x8*)(const void*)&A_lds[r * 128 + ((ks * 32 + 8 * g) ^ ((r & 7) << 3))];
            }
            #pragma unroll
            for (int m = 0; m < 4; ++m)
                #pragma unroll
                for (int n = 0; n < 4; ++n)
                    acc[m][n] = __builtin_amdgcn_mfma_f32_16x16x32_bf16(af[m], Bf[n][ks], acc[m][n], 0, 0, 0);
        }
        unsigned short* dst = p ? Q : P;
        #pragma unroll
        for (int m = 0; m < 4; ++m)
            #pragma unroll
            for (int rr = 0; rr < 4; ++rr) {
                int row = m * 16 + 4 * g + rr;
                int nd = r0 + row;
                if (nd < NNODES) {
                    #pragma unroll
                    for (int n = 0; n < 4; ++n) {
                        int col = w * 64 + n * 16 + l15;
                        float v = acc[m][n][rr] + (p ? 0.f : b1r[n]);
                        dst[(size_t)nd * NH + col] = f2bf(v);
                    }
                }
            }
    }
}

// ---------------- edge kernel ----------------
// r12 structure. Changes: p/q held in regs (no xb pack in gather — value-identical);
// M pack via v_cvt_pk_bf16_f32 (RNE, single-instr per pair); batched epilogue reads.
__global__ __launch_bounds__(256, 3)
void edge_kernel(const unsigned short* __restrict__ P,
                 const unsigned short* __restrict__ Q,
                 const unsigned short* __restrict__ ssrc,
                 const unsigned short* __restrict__ sdst,
                 const unsigned short* __restrict__ Wt2,
                 const float* __restrict__ g1, const float* __restrict__ be1,
                 const float* __restrict__ b2,
                 float* __restrict__ agg)
{
    // union region: M bf16 64x256 (B1..B4) | S f32 32x260 half-tile (post-B4)
    __shared__ __align__(16) char smem[33280];
    unsigned short* M_lds = (unsigned short*)smem;
    float* S = (float*)smem;
    __shared__ float s_part[4][64][2];
    __shared__ unsigned short s_src[64];
    __shared__ __align__(16) float s_g1[256], s_be1[256];

    const int tid = threadIdx.x;
    const int lane = tid & 63;
    const int w = tid >> 6;
    const int l15 = lane & 15;
    const int g = lane >> 4;
    const int e0 = blockIdx.x * 64;
    const int r = lane;  // thread's row (edge slot); wave w owns cols [w*64, w*64+64)

    s_g1[tid] = g1[tid]; s_be1[tid] = be1[tid];
    if (tid < 64) s_src[tid] = ssrc[e0 + tid];

    // ---- gather p,q into regs; stats on exact f32 (same order as r12) ----
    int nds = ssrc[e0 + r];
    int ndt = sdst[e0 + r];
    const bf16x8* Pp = (const bf16x8*)(const void*)(P + (size_t)nds * NH + w * 64);
    const bf16x8* Qp = (const bf16x8*)(const void*)(Q + (size_t)ndt * NH + w * 64);

    bf16x8 pv[8], qv[8];
    #pragma unroll
    for (int j = 0; j < 8; ++j) { pv[j] = Pp[j]; qv[j] = Qp[j]; }

    float sum = 0.f, sq = 0.f;
    #pragma unroll
    for (int j = 0; j < 8; ++j) {
        #pragma unroll
        for (int k = 0; k < 8; ++k) {
            float xx = (float)pv[j][k] + (float)qv[j][k];
            sum += xx;
            sq += xx * xx;
        }
    }
    s_part[w][r][0] = sum;
    s_part[w][r][1] = sq;
    __syncthreads();                                   // B1: partials visible

    // ---- all-thread LN finalize (each thread reduces its own row) ----
    float mean, rstd;
    {
        float s = s_part[0][r][0] + s_part[1][r][0] + s_part[2][r][0] + s_part[3][r][0];
        float q = s_part[0][r][1] + s_part[1][r][1] + s_part[2][r][1] + s_part[3][r][1];
        mean = s * (1.f / 256.f);
        float var = q * (1.f / 256.f) - mean * mean;
        rstd = rsqrtf(var + 1e-5f);
    }

    // ---- LN apply + SiLU -> M tile (cvt_pk pack, swizzled b128 chunk writes) ----
    {
        #pragma unroll
        for (int j = 0; j < 8; ++j) {
            float ga[8], bb[8];
            *(float4*)&ga[0] = *(const float4*)&s_g1[w * 64 + j * 8];
            *(float4*)&ga[4] = *(const float4*)&s_g1[w * 64 + j * 8 + 4];
            *(float4*)&bb[0] = *(const float4*)&s_be1[w * 64 + j * 8];
            *(float4*)&bb[4] = *(const float4*)&s_be1[w * 64 + j * 8 + 4];
            float yv[8];
            #pragma unroll
            for (int k = 0; k < 8; ++k) {
                float xx = (float)pv[j][k] + (float)qv[j][k];
                float y = (xx - mean) * rstd * ga[k] + bb[k];
                yv[k] = y * (1.f / (1.f + __expf(-y)));
            }
            uint4 mv;
            mv.x = cvtpk(yv[0], yv[1]);
            mv.y = cvtpk(yv[2], yv[3]);
            mv.z = cvtpk(yv[4], yv[5]);
            mv.w = cvtpk(yv[6], yv[7]);
            *(uint4*)(void*)&M_lds[r * 256 + w * 64 + ((j ^ (r & 7)) * 8)] = mv;
        }
    }
    __syncthreads();                                   // B3: M ready (pv/qv dead)

    // ---- GEMM2: m[64x256] @ W2, W2 frags loaded per-ks (short live range) ----
    f32x4 acc2[4][4] = {};
    #pragma unroll
    for (int ks = 0; ks < 8; ++ks) {
        bf16x8 bfr[4];
        #pragma unroll
        for (int n = 0; n < 4; ++n) {
            int cn = w * 64 + n * 16 + l15;
            bfr[n] = *(const bf16x8*)(const void*)&Wt2[cn * 256 + ks * 32 + 8 * g];
        }
        bf16x8 af[4];
        #pragma unroll
        for (int m = 0; m < 4; ++m) {
            int rr_ = m * 16 + l15;
            af[m] = *(const bf16x8*)(const void*)&M_lds[rr_ * 256 + ((ks * 32 + 8 * g) ^ ((rr_ & 7) << 3))];
        }
        #pragma unroll
        for (int m = 0; m < 4; ++m)
            #pragma unroll
            for (int n = 0; n < 4; ++n)
                acc2[m][n] = __builtin_amdgcn_mfma_f32_16x16x32_bf16(af[m], bfr[n], acc2[m][n], 0, 0, 0);
    }
    __syncthreads();                                   // B4: M reads done, S may overlay

    // ---- split epilogue: two 32-row S half-tiles; batched 8-wide run-reduce ----
    {
        float b2r[4];
        #pragma unroll
        for (int n = 0; n < 4; ++n) b2r[n] = b2[w * 64 + n * 16 + l15];

        const int col = tid;
        float run = 0.f;
        int prev = s_src[0];
        #pragma unroll
        for (int p = 0; p < 2; ++p) {
            #pragma unroll
            for (int mm = 0; mm < 2; ++mm) {
                int m = 2 * p + mm;
                #pragma unroll
                for (int rr = 0; rr < 4; ++rr) {
                    int lrow = mm * 16 + 4 * g + rr;   // local row in half-tile
                    #pragma unroll
                    for (int n = 0; n < 4; ++n) {
                        int c2 = w * 64 + n * 16 + l15;
                        S[lrow * 260 + c2] = acc2[m][n][rr] + b2r[n];
                    }
                }
            }
            __syncthreads();                           // S half ready
            #pragma unroll 1
            for (int c8 = 0; c8 < 4; ++c8) {
                float v[8];
                int nd8[8];
                #pragma unroll
                for (int u = 0; u < 8; ++u) v[u] = S[(c8 * 8 + u) * 260 + col];
                #pragma unroll
                for (int u = 0; u < 8; ++u) nd8[u] = s_src[32 * p + c8 * 8 + u];
                #pragma unroll
                for (int u = 0; u < 8; ++u) {
                    if (nd8[u] != prev) {
                        atomicAdd(&agg[(size_t)prev * NH + col], run);
                        run = 0.f;
                        prev = nd8[u];
                    }
                    run += v[u];
                }
            }
            if (p == 0) __syncthreads();               // protect S before overwrite
        }
        atomicAdd(&agg[(size_t)prev * NH + col], run);
    }
}

// ---------------- node kernel ----------------
// Lazy W3/W4 fragments from global (L2-hot) — B_lds deleted; LDS ~45 KB -> 3 blocks/CU.
__global__ __launch_bounds__(256, 3)
void node_kernel(const float* __restrict__ h,
                 const float* __restrict__ agg,
                 const unsigned short* __restrict__ Wt3,
                 const unsigned short* __restrict__ Wt4,
                 const float* __restrict__ b3, const float* __restrict__ g2,
                 const float* __restrict__ be2, const float* __restrict__ b4,
                 float* __restrict__ out)
{
    __shared__ __align__(16) unsigned short A_lds[64 * 64];
    __shared__ __align__(16) unsigned short M_lds[64 * 256];
    __shared__ float s_mr[64][2];
    __shared__ float s_b3[256], s_g2[256], s_be2[256], s_b4[128];

    const int tid = threadIdx.x;
    const int lane = tid & 63;
    const int w = tid >> 6;
    const int l15 = lane & 15;
    const int g = lane >> 4;
    const int r0 = blockIdx.x * 64;

    s_b3[tid] = b3[tid]; s_g2[tid] = g2[tid]; s_be2[tid] = be2[tid];
    if (tid < 128) s_b4[tid] = b4[tid];
    __syncthreads();

    f32x4 acc[4][4] = {};

    for (int kt = 0; kt < 6; ++kt) {
        // A reg-stage (f32 -> bf16, swizzled chunks)
        #pragma unroll
        for (int i = 0; i < 2; ++i) {
            int idx = i * 256 + tid;
            int row = idx >> 3, cl = idx & 7;
            int nd = r0 + row; if (nd >= NNODES) nd = NNODES - 1;
            int scol = (cl ^ (row & 7)) * 8;
            const float* sp = (kt < 2) ? (h + (size_t)nd * NF + kt * 64 + scol)
                                       : (agg + (size_t)nd * NH + (kt - 2) * 64 + scol);
            float4 va = *(const float4*)sp;
            float4 vb = *(const float4*)(sp + 4);
            u16x8 mv;
            mv[0] = f2bf(va.x); mv[1] = f2bf(va.y); mv[2] = f2bf(va.z); mv[3] = f2bf(va.w);
            mv[4] = f2bf(vb.x); mv[5] = f2bf(vb.y); mv[6] = f2bf(vb.z); mv[7] = f2bf(vb.w);
            *(u16x8*)(void*)&A_lds[row * 64 + cl * 8] = mv;
        }
        __syncthreads();
        #pragma unroll
        for (int kk = 0; kk < 2; ++kk) {
            int ke = kk * 32 + 8 * g;
            bf16x8 af[4], bfr[4];
            #pragma unroll
            for (int m = 0; m < 4; ++m) {
                int rr_ = m * 16 + l15;
                af[m] = *(const bf16x8*)(const void*)&A_lds[rr_ * 64 + (ke ^ ((rr_ & 7) << 3))];
            }
            #pragma unroll
            for (int n = 0; n < 4; ++n) {
                int cn = w * 64 + n * 16 + l15;
                bfr[n] = *(const bf16x8*)(const void*)&Wt3[(size_t)cn * 384 + kt * 64 + ke];
            }
            #pragma unroll
            for (int m = 0; m < 4; ++m)
                #pragma unroll
                for (int n = 0; n < 4; ++n)
                    acc[m][n] = __builtin_amdgcn_mfma_f32_16x16x32_bf16(af[m], bfr[n], acc[m][n], 0, 0, 0);
        }
        __syncthreads();
    }

    float psum[4][4], psq[4][4];
    #pragma unroll
    for (int m = 0; m < 4; ++m)
        #pragma unroll
        for (int rr = 0; rr < 4; ++rr) { psum[m][rr] = 0.f; psq[m][rr] = 0.f; }
    #pragma unroll
    for (int m = 0; m < 4; ++m)
        #pragma unroll
        for (int n = 0; n < 4; ++n) {
            int col = w * 64 + n * 16 + l15;
            float bb = s_b3[col];
            #pragma unroll
            for (int rr = 0; rr < 4; ++rr) {
                float xv = acc[m][n][rr] + bb;
                acc[m][n][rr] = xv;
                psum[m][rr] += xv;
                psq[m][rr] += xv * xv;
            }
        }
    #pragma unroll
    for (int m = 0; m < 4; ++m)
        #pragma unroll
        for (int rr = 0; rr < 4; ++rr) {
            float s = psum[m][rr], q = psq[m][rr];
            s += __shfl_xor(s, 1); s += __shfl_xor(s, 2); s += __shfl_xor(s, 4); s += __shfl_xor(s, 8);
            q += __shfl_xor(q, 1); q += __shfl_xor(q, 2); q += __shfl_xor(q, 4); q += __shfl_xor(q, 8);
            psum[m][rr] = s; psq[m][rr] = q;
        }
    float vs = 0.f, vq = 0.f;
    #pragma unroll
    for (int m = 0; m < 4; ++m)
        #pragma unroll
        for (int rr = 0; rr < 4; ++rr) {
            bool sel = (l15 == m * 4 + rr);
            vs = sel ? psum[m][rr] : vs;
            vq = sel ? psq[m][rr] : vq;
        }
    float (*s_part)[64][2] = (float(*)[64][2])(void*)M_lds;
    {
        int row = (l15 >> 2) * 16 + 4 * g + (l15 & 3);
        s_part[w][row][0] = vs;
        s_part[w][row][1] = vq;
    }
    __syncthreads();
    if (tid < 64) {
        float s = s_part[0][tid][0] + s_part[1][tid][0] + s_part[2][tid][0] + s_part[3][tid][0];
        float q = s_part[0][tid][1] + s_part[1][tid][1] + s_part[2][tid][1] + s_part[3][tid][1];
        float mean = s * (1.f / 256.f);
        float var = q * (1.f / 256.f) - mean * mean;
        s_mr[tid][0] = mean;
        s_mr[tid][1] = rsqrtf(var + 1e-5f);
    }
    __syncthreads();

    #pragma unroll
    for (int m = 0; m < 4; ++m)
        #pragma unroll
        for (int rr = 0; rr < 4; ++rr) {
            int row = m * 16 + 4 * g + rr;
            float mean = s_mr[row][0], rstd = s_mr[row][1];
            #pragma unroll
            for (int n = 0; n < 4; ++n) {
                int col = w * 64 + n * 16 + l15;
                float y = (acc[m][n][rr] - mean) * rstd * s_g2[col] + s_be2[col];
                float sy = y * (1.f / (1.f + __expf(-y)));
                M_lds[row * 256 + (col ^ ((row & 7) << 3))] = f2bf(sy);
            }
        }
    __syncthreads();

    // ---- GEMM4: m[64x256] @ W4 (N=128), W4 frags lazy from global; no barriers ----
    f32x4 acc4[4][2] = {};
    for (int kt = 0; kt < 4; ++kt) {
        #pragma unroll
        for (int kk = 0; kk < 2; ++kk) {
            int keB = kk * 32 + 8 * g;
            int keA = kt * 64 + keB;
            bf16x8 af[4], bfr[2];
            #pragma unroll
            for (int m = 0; m < 4; ++m) {
                int rr_ = m * 16 + l15;
                af[m] = *(const bf16x8*)(const void*)&M_lds[rr_ * 256 + (keA ^ ((rr_ & 7) << 3))];
            }
            #pragma unroll
            for (int n2 = 0; n2 < 2; ++n2) {
                int cn = w * 32 + n2 * 16 + l15;
                bfr[n2] = *(const bf16x8*)(const void*)&Wt4[(size_t)cn * 256 + kt * 64 + keB];
            }
            #pragma unroll
            for (int m = 0; m < 4; ++m)
                #pragma unroll
                for (int n2 = 0; n2 < 2; ++n2)
                    acc4[m][n2] = __builtin_amdgcn_mfma_f32_16x16x32_bf16(af[m], bfr[n2], acc4[m][n2], 0, 0, 0);
        }
    }

    #pragma unroll
    for (int m = 0; m < 4; ++m)
        #pragma unroll
        for (int rr = 0; rr < 4; ++rr) {
            int row = m * 16 + 4 * g + rr;
            int nd = r0 + row;
            if (nd < NNODES) {
                #pragma unroll
                for (int n2 = 0; n2 < 2; ++n2) {
                    int col = w * 32 + n2 * 16 + l15;
                    out[(size_t)nd * NF + col] = h[(size_t)nd * NF + col] + acc4[m][n2][rr] + s_b4[col];
                }
            }
        }
}

extern "C" void kernel_launch(void* const* d_in, const int* in_sizes, int n_in,
                              void* d_out, int out_size, void* d_ws, size_t ws_size,
                              hipStream_t stream) {
    const float* h   = (const float*)d_in[0];
    const int* ei    = (const int*)d_in[1];
    const float* W1  = (const float*)d_in[2];
    const float* b1  = (const float*)d_in[3];
    const float* g1  = (const float*)d_in[4];
    const float* be1 = (const float*)d_in[5];
    const float* W2  = (const float*)d_in[6];
    const float* b2  = (const float*)d_in[7];
    const float* W3  = (const float*)d_in[8];
    const float* b3  = (const float*)d_in[9];
    const float* g2  = (const float*)d_in[10];
    const float* be2 = (const float*)d_in[11];
    const float* W4  = (const float*)d_in[12];
    const float* b4  = (const float*)d_in[13];
    float* out = (float*)d_out;

    char* ws = (char*)d_ws;
    float* agg            = (float*)(ws);                      // 51,200,000 B [edge->node]
    // cnt/basep/cursor overlay agg: live only [hist -> scatter], agg memset after
    int* cnt              = (int*)(ws);                        // 200,000 B
    int* basep            = (int*)(ws + 200000);               // 200,000 B
    int* cursor           = (int*)(ws + 400000);               // 200,000 B
    unsigned short* P     = (unsigned short*)(ws + 51200000);  // 25,600,000 B [pq->edge]
    unsigned short* Q     = (unsigned short*)d_out;            // 25,600,000 B [pq->edge], dead before node writes out
    unsigned short* ssrc  = (unsigned short*)(ws + 76800000);  // 1,600,000 B
    unsigned short* sdst  = (unsigned short*)(ws + 78400000);  // 1,600,000 B
    unsigned short* Wtpq  = (unsigned short*)(ws + 80000000);  // 131,072 B
    unsigned short* Wt2   = (unsigned short*)(ws + 80131072);  // 131,072 B
    unsigned short* Wt3   = (unsigned short*)(ws + 80262144);  // 196,608 B
    unsigned short* Wt4   = (unsigned short*)(ws + 80458752);  // 65,536 B  (end ~80.5 MB)

    hipMemsetAsync(ws, 0, 600000, stream);  // zero cnt/basep/cursor

    wpq_kernel<<<(512 * 128 + 255) / 256, 256, 0, stream>>>(W1, Wtpq);
    tcvt_kernel<<<(256 * 256 + 255) / 256, 256, 0, stream>>>(W2, Wt2, 256, 256);
    tcvt_kernel<<<(384 * 256 + 255) / 256, 256, 0, stream>>>(W3, Wt3, 384, 256);
    tcvt_kernel<<<(256 * 128 + 255) / 256, 256, 0, stream>>>(W4, Wt4, 256, 128);

    hist_kernel<<<(NEDGES + 255) / 256, 256, 0, stream>>>(ei, cnt);
    scan_kernel<<<1, 1024, 0, stream>>>(cnt, basep, NNODES);
    scatter_kernel<<<(NEDGES + 255) / 256, 256, 0, stream>>>(ei, basep, cursor, ssrc, sdst);

    pq_kernel<<<(NNODES + 63) / 64, 256, 0, stream>>>(h, Wtpq, b1, P, Q);

    hipMemsetAsync(agg, 0, (size_t)NNODES * NH * sizeof(float), stream);  // cnt region dead now

    edge_kernel<<<NEDGES / 64, 256, 0, stream>>>(P, Q, ssrc, sdst, Wt2, g1, be1, b2, agg);
    node_kernel<<<(NNODES + 63) / 64, 256, 0, stream>>>(h, agg, Wt3, Wt4, b3, g2, be2, b4, out);
}

// Round 14
// 552.284 us; speedup vs baseline: 1.0267x; 1.0267x over previous
//
#include <hip/hip_runtime.h>
#include <hip/hip_bf16.h>
#include <stdint.h>

#define NNODES 50000
#define NEDGES 800000
#define NF 128
#define NH 256

typedef __attribute__((ext_vector_type(8))) __bf16 bf16x8;
typedef __attribute__((ext_vector_type(8))) unsigned short u16x8;
typedef __attribute__((ext_vector_type(4))) float f32x4;

__device__ __forceinline__ unsigned short f2bf(float f) {
    union { float f; unsigned int u; } v; v.f = f;
    unsigned int r = v.u + 0x7fffu + ((v.u >> 16) & 1u);
    return (unsigned short)(r >> 16);
}

// packed f32x2 -> bf16x2 (RNE on gfx950; refcheck-proven r13: absmax identical to f2bf)
__device__ __forceinline__ unsigned int cvtpk(float lo, float hi) {
    unsigned int r;
    asm volatile("v_cvt_pk_bf16_f32 %0, %1, %2" : "=v"(r) : "v"(lo), "v"(hi));
    return r;
}

__device__ __forceinline__ void gload16(const void* g, void* l) {
    __builtin_amdgcn_global_load_lds(
        (const __attribute__((address_space(1))) void*)g,
        (__attribute__((address_space(3))) void*)l,
        16, 0, 0);
}

// W [K][Nn] f32 row-major -> Wt [Nn][K] bf16
__global__ __launch_bounds__(256) void tcvt_kernel(const float* __restrict__ W,
                                                   unsigned short* __restrict__ Wt, int K, int Nn) {
    int i = blockIdx.x * 256 + threadIdx.x;
    if (i < K * Nn) {
        int k = i / Nn, n = i - k * Nn;
        Wt[n * K + k] = f2bf(W[i]);
    }
}

// W1 [256][256] f32 -> Wtpq [512][128] bf16 : n<256 -> W1a col n; n>=256 -> W1b col n-256
__global__ __launch_bounds__(256) void wpq_kernel(const float* __restrict__ W1,
                                                  unsigned short* __restrict__ Wtpq) {
    int i = blockIdx.x * 256 + threadIdx.x;
    if (i < 512 * 128) {
        int n = i >> 7, k = i & 127;
        float v = (n < 256) ? W1[k * 256 + n] : W1[(128 + k) * 256 + (n - 256)];
        Wtpq[i] = f2bf(v);
    }
}

// ---------------- sort-by-row kernels ----------------
__global__ __launch_bounds__(256) void hist_kernel(const int* __restrict__ row, int* __restrict__ cnt) {
    int e = blockIdx.x * 256 + threadIdx.x;
    if (e < NEDGES) atomicAdd(&cnt[row[e]], 1);
}

__global__ __launch_bounds__(1024) void scan_kernel(const int* __restrict__ cnt, int* __restrict__ base, int n) {
    __shared__ int wsum[16];
    __shared__ int s_carry;
    const int tid = threadIdx.x;
    const int lane = tid & 63;
    const int wv = tid >> 6;
    if (tid == 0) s_carry = 0;
    __syncthreads();
    for (int off = 0; off < n; off += 1024) {
        int v = (off + tid < n) ? cnt[off + tid] : 0;
        int acc = v;
        #pragma unroll
        for (int s = 1; s < 64; s <<= 1) {
            int t = __shfl_up(acc, s);
            if (lane >= s) acc += t;
        }
        if (lane == 63) wsum[wv] = acc;
        __syncthreads();
        if (wv == 0) {
            int x = (lane < 16) ? wsum[lane] : 0;
            #pragma unroll
            for (int s = 1; s < 16; s <<= 1) {
                int t = __shfl_up(x, s);
                if (lane >= s) x += t;
            }
            if (lane < 16) wsum[lane] = x;
        }
        __syncthreads();
        int c = s_carry;
        int wtot = __shfl(acc, 63);
        int woff = wsum[wv] - wtot;
        if (off + tid < n) base[off + tid] = c + woff + acc - v;
        __syncthreads();
        if (tid == 0) s_carry = c + wsum[15];
        __syncthreads();
    }
}

__global__ __launch_bounds__(256) void scatter_kernel(const int* __restrict__ ei,
                                                      const int* __restrict__ base,
                                                      int* __restrict__ cursor,
                                                      unsigned short* __restrict__ ssrc,
                                                      unsigned short* __restrict__ sdst) {
    int e = blockIdx.x * 256 + threadIdx.x;
    if (e < NEDGES) {
        int r = ei[e];
        int c = ei[NEDGES + e];
        int pos = base[r] + atomicAdd(&cursor[r], 1);
        ssrc[pos] = (unsigned short)r;
        sdst[pos] = (unsigned short)c;
    }
}

// ---------------- P/Q precompute ----------------
// P = h@W1a + b1, Q = h@W1b  (both [NNODES][256] bf16). BM=64, K=128, 4 waves.
__global__ __launch_bounds__(256, 2)
void pq_kernel(const float* __restrict__ h,
               const unsigned short* __restrict__ Wtpq,
               const float* __restrict__ b1,
               unsigned short* __restrict__ P,
               unsigned short* __restrict__ Q)
{
    __shared__ __align__(16) unsigned short A_lds[64 * 128];
    const int tid = threadIdx.x;
    const int lane = tid & 63;
    const int w = tid >> 6;
    const int l15 = lane & 15;
    const int g = lane >> 4;
    const int r0 = blockIdx.x * 64;

    float b1r[4];
    #pragma unroll
    for (int n = 0; n < 4; ++n) b1r[n] = b1[w * 64 + n * 16 + l15];

    // reg-stage A (h f32 -> bf16, swizzled chunks)
    #pragma unroll
    for (int i = 0; i < 4; ++i) {
        int idx = i * 256 + tid;
        int row = idx >> 4, cl = idx & 15;
        int nd = r0 + row; if (nd >= NNODES) nd = NNODES - 1;
        const float* sp = h + (size_t)nd * NF + ((cl ^ (row & 7)) * 8);
        float4 va = *(const float4*)sp;
        float4 vb = *(const float4*)(sp + 4);
        u16x8 mv;
        mv[0] = f2bf(va.x); mv[1] = f2bf(va.y); mv[2] = f2bf(va.z); mv[3] = f2bf(va.w);
        mv[4] = f2bf(vb.x); mv[5] = f2bf(vb.y); mv[6] = f2bf(vb.z); mv[7] = f2bf(vb.w);
        *(u16x8*)(void*)&A_lds[row * 128 + cl * 8] = mv;
    }
    __syncthreads();

    #pragma unroll
    for (int p = 0; p < 2; ++p) {
        bf16x8 Bf[4][4];
        #pragma unroll
        for (int n = 0; n < 4; ++n) {
            int cn = w * 64 + n * 16 + l15;
            #pragma unroll
            for (int ks = 0; ks < 4; ++ks)
                Bf[n][ks] = *(const bf16x8*)(const void*)&Wtpq[(size_t)(p * 256 + cn) * 128 + ks * 32 + 8 * g];
        }
        f32x4 acc[4][4] = {};
        #pragma unroll
        for (int ks = 0; ks < 4; ++ks) {
            bf16x8 af[4];
            #pragma unroll
            for (int m = 0; m < 4; ++m) {
                int r = m * 16 + l15;
                af[m] = *(const bf16x8*)(const void*)&A_lds[r * 128 + ((ks * 32 + 8 * g) ^ ((r & 7) << 3))];
            }
            #pragma unroll
            for (int m = 0; m < 4; ++m)
                #pragma unroll
                for (int n = 0; n < 4; ++n)
                    acc[m][n] = __builtin_amdgcn_mfma_f32_16x16x32_bf16(af[m], Bf[n][ks], acc[m][n], 0, 0, 0);
        }
        unsigned short* dst = p ? Q : P;
        #pragma unroll
        for (int m = 0; m < 4; ++m)
            #pragma unroll
            for (int rr = 0; rr < 4; ++rr) {
                int row = m * 16 + 4 * g + rr;
                int nd = r0 + row;
                if (nd < NNODES) {
                    #pragma unroll
                    for (int n = 0; n < 4; ++n) {
                        int col = w * 64 + n * 16 + l15;
                        float v = acc[m][n][rr] + (p ? 0.f : b1r[n]);
                        dst[(size_t)nd * NH + col] = f2bf(v);
                    }
                }
            }
    }
}

// ---------------- edge kernel ----------------
// r12 register shape (xb packed across B1, 32 VGPR) + r13 cheap instructions
// (cvtpk packs, batched epilogue). Stats on exact f32 (r12 order).
__global__ __launch_bounds__(256, 3)
void edge_kernel(const unsigned short* __restrict__ P,
                 const unsigned short* __restrict__ Q,
                 const unsigned short* __restrict__ ssrc,
                 const unsigned short* __restrict__ sdst,
                 const unsigned short* __restrict__ Wt2,
                 const float* __restrict__ g1, const float* __restrict__ be1,
                 const float* __restrict__ b2,
                 float* __restrict__ agg)
{
    // union region: M bf16 64x256 (B1..B4) | S f32 32x260 half-tile (post-B4)
    __shared__ __align__(16) char smem[33280];
    unsigned short* M_lds = (unsigned short*)smem;
    float* S = (float*)smem;
    __shared__ float s_part[4][64][2];
    __shared__ unsigned short s_src[64];
    __shared__ __align__(16) float s_g1[256], s_be1[256];

    const int tid = threadIdx.x;
    const int lane = tid & 63;
    const int w = tid >> 6;
    const int l15 = lane & 15;
    const int g = lane >> 4;
    const int e0 = blockIdx.x * 64;
    const int r = lane;  // thread's row (edge slot); wave w owns cols [w*64, w*64+64)

    s_g1[tid] = g1[tid]; s_be1[tid] = be1[tid];
    if (tid < 64) s_src[tid] = ssrc[e0 + tid];

    // ---- gather x = P[src] + Q[tgt]; stats on exact f32; pack xb via cvtpk ----
    int nds = ssrc[e0 + r];
    int ndt = sdst[e0 + r];
    const bf16x8* Pp = (const bf16x8*)(const void*)(P + (size_t)nds * NH + w * 64);
    const bf16x8* Qp = (const bf16x8*)(const void*)(Q + (size_t)ndt * NH + w * 64);

    uint4 xb[8];
    float sum = 0.f, sq = 0.f;
    #pragma unroll
    for (int j = 0; j < 8; ++j) {
        bf16x8 pv = Pp[j];
        bf16x8 qv = Qp[j];
        float xx[8];
        #pragma unroll
        for (int k = 0; k < 8; ++k) {
            xx[k] = (float)pv[k] + (float)qv[k];
            sum += xx[k];
            sq += xx[k] * xx[k];
        }
        xb[j].x = cvtpk(xx[0], xx[1]);
        xb[j].y = cvtpk(xx[2], xx[3]);
        xb[j].z = cvtpk(xx[4], xx[5]);
        xb[j].w = cvtpk(xx[6], xx[7]);
    }
    s_part[w][r][0] = sum;
    s_part[w][r][1] = sq;
    __syncthreads();                                   // B1: partials visible

    // ---- all-thread LN finalize (each thread reduces its own row) ----
    float mean, rstd;
    {
        float s = s_part[0][r][0] + s_part[1][r][0] + s_part[2][r][0] + s_part[3][r][0];
        float q = s_part[0][r][1] + s_part[1][r][1] + s_part[2][r][1] + s_part[3][r][1];
        mean = s * (1.f / 256.f);
        float var = q * (1.f / 256.f) - mean * mean;
        rstd = rsqrtf(var + 1e-5f);
    }

    // ---- LN apply + SiLU -> M tile (cvtpk pack, swizzled b128 chunk writes) ----
    {
        #pragma unroll
        for (int j = 0; j < 8; ++j) {
            bf16x8 xv = *(bf16x8*)(void*)&xb[j];
            float ga[8], bb[8];
            *(float4*)&ga[0] = *(const float4*)&s_g1[w * 64 + j * 8];
            *(float4*)&ga[4] = *(const float4*)&s_g1[w * 64 + j * 8 + 4];
            *(float4*)&bb[0] = *(const float4*)&s_be1[w * 64 + j * 8];
            *(float4*)&bb[4] = *(const float4*)&s_be1[w * 64 + j * 8 + 4];
            float yv[8];
            #pragma unroll
            for (int k = 0; k < 8; ++k) {
                float xx = (float)xv[k];
                float y = (xx - mean) * rstd * ga[k] + bb[k];
                yv[k] = y * (1.f / (1.f + __expf(-y)));
            }
            uint4 mv;
            mv.x = cvtpk(yv[0], yv[1]);
            mv.y = cvtpk(yv[2], yv[3]);
            mv.z = cvtpk(yv[4], yv[5]);
            mv.w = cvtpk(yv[6], yv[7]);
            *(uint4*)(void*)&M_lds[r * 256 + w * 64 + ((j ^ (r & 7)) * 8)] = mv;
        }
    }
    __syncthreads();                                   // B3: M ready (xb dead)

    // ---- GEMM2: m[64x256] @ W2, W2 frags loaded per-ks (short live range) ----
    f32x4 acc2[4][4] = {};
    #pragma unroll
    for (int ks = 0; ks < 8; ++ks) {
        bf16x8 bfr[4];
        #pragma unroll
        for (int n = 0; n < 4; ++n) {
            int cn = w * 64 + n * 16 + l15;
            bfr[n] = *(const bf16x8*)(const void*)&Wt2[cn * 256 + ks * 32 + 8 * g];
        }
        bf16x8 af[4];
        #pragma unroll
        for (int m = 0; m < 4; ++m) {
            int rr_ = m * 16 + l15;
            af[m] = *(const bf16x8*)(const void*)&M_lds[rr_ * 256 + ((ks * 32 + 8 * g) ^ ((rr_ & 7) << 3))];
        }
        #pragma unroll
        for (int m = 0; m < 4; ++m)
            #pragma unroll
            for (int n = 0; n < 4; ++n)
                acc2[m][n] = __builtin_amdgcn_mfma_f32_16x16x32_bf16(af[m], bfr[n], acc2[m][n], 0, 0, 0);
    }
    __syncthreads();                                   // B4: M reads done, S may overlay

    // ---- split epilogue: two 32-row S half-tiles; batched 8-wide run-reduce ----
    {
        float b2r[4];
        #pragma unroll
        for (int n = 0; n < 4; ++n) b2r[n] = b2[w * 64 + n * 16 + l15];

        const int col = tid;
        float run = 0.f;
        int prev = s_src[0];
        #pragma unroll
        for (int p = 0; p < 2; ++p) {
            #pragma unroll
            for (int mm = 0; mm < 2; ++mm) {
                int m = 2 * p + mm;
                #pragma unroll
                for (int rr = 0; rr < 4; ++rr) {
                    int lrow = mm * 16 + 4 * g + rr;   // local row in half-tile
                    #pragma unroll
                    for (int n = 0; n < 4; ++n) {
                        int c2 = w * 64 + n * 16 + l15;
                        S[lrow * 260 + c2] = acc2[m][n][rr] + b2r[n];
                    }
                }
            }
            __syncthreads();                           // S half ready
            #pragma unroll 1
            for (int c8 = 0; c8 < 4; ++c8) {
                float v[8];
                int nd8[8];
                #pragma unroll
                for (int u = 0; u < 8; ++u) v[u] = S[(c8 * 8 + u) * 260 + col];
                #pragma unroll
                for (int u = 0; u < 8; ++u) nd8[u] = s_src[32 * p + c8 * 8 + u];
                #pragma unroll
                for (int u = 0; u < 8; ++u) {
                    if (nd8[u] != prev) {
                        atomicAdd(&agg[(size_t)prev * NH + col], run);
                        run = 0.f;
                        prev = nd8[u];
                    }
                    run += v[u];
                }
            }
            if (p == 0) __syncthreads();               // protect S before overwrite
        }
        atomicAdd(&agg[(size_t)prev * NH + col], run);
    }
}

// ---------------- node kernel ----------------
// Lazy W3/W4 fragments from global (L2-hot) — B_lds deleted; LDS ~45 KB -> 3 blocks/CU.
__global__ __launch_bounds__(256, 3)
void node_kernel(const float* __restrict__ h,
                 const float* __restrict__ agg,
                 const unsigned short* __restrict__ Wt3,
                 const unsigned short* __restrict__ Wt4,
                 const float* __restrict__ b3, const float* __restrict__ g2,
                 const float* __restrict__ be2, const float* __restrict__ b4,
                 float* __restrict__ out)
{
    __shared__ __align__(16) unsigned short A_lds[64 * 64];
    __shared__ __align__(16) unsigned short M_lds[64 * 256];
    __shared__ float s_mr[64][2];
    __shared__ float s_b3[256], s_g2[256], s_be2[256], s_b4[128];

    const int tid = threadIdx.x;
    const int lane = tid & 63;
    const int w = tid >> 6;
    const int l15 = lane & 15;
    const int g = lane >> 4;
    const int r0 = blockIdx.x * 64;

    s_b3[tid] = b3[tid]; s_g2[tid] = g2[tid]; s_be2[tid] = be2[tid];
    if (tid < 128) s_b4[tid] = b4[tid];
    __syncthreads();

    f32x4 acc[4][4] = {};

    for (int kt = 0; kt < 6; ++kt) {
        // A reg-stage (f32 -> bf16, swizzled chunks)
        #pragma unroll
        for (int i = 0; i < 2; ++i) {
            int idx = i * 256 + tid;
            int row = idx >> 3, cl = idx & 7;
            int nd = r0 + row; if (nd >= NNODES) nd = NNODES - 1;
            int scol = (cl ^ (row & 7)) * 8;
            const float* sp = (kt < 2) ? (h + (size_t)nd * NF + kt * 64 + scol)
                                       : (agg + (size_t)nd * NH + (kt - 2) * 64 + scol);
            float4 va = *(const float4*)sp;
            float4 vb = *(const float4*)(sp + 4);
            u16x8 mv;
            mv[0] = f2bf(va.x); mv[1] = f2bf(va.y); mv[2] = f2bf(va.z); mv[3] = f2bf(va.w);
            mv[4] = f2bf(vb.x); mv[5] = f2bf(vb.y); mv[6] = f2bf(vb.z); mv[7] = f2bf(vb.w);
            *(u16x8*)(void*)&A_lds[row * 64 + cl * 8] = mv;
        }
        __syncthreads();
        #pragma unroll
        for (int kk = 0; kk < 2; ++kk) {
            int ke = kk * 32 + 8 * g;
            bf16x8 af[4], bfr[4];
            #pragma unroll
            for (int m = 0; m < 4; ++m) {
                int rr_ = m * 16 + l15;
                af[m] = *(const bf16x8*)(const void*)&A_lds[rr_ * 64 + (ke ^ ((rr_ & 7) << 3))];
            }
            #pragma unroll
            for (int n = 0; n < 4; ++n) {
                int cn = w * 64 + n * 16 + l15;
                bfr[n] = *(const bf16x8*)(const void*)&Wt3[(size_t)cn * 384 + kt * 64 + ke];
            }
            #pragma unroll
            for (int m = 0; m < 4; ++m)
                #pragma unroll
                for (int n = 0; n < 4; ++n)
                    acc[m][n] = __builtin_amdgcn_mfma_f32_16x16x32_bf16(af[m], bfr[n], acc[m][n], 0, 0, 0);
        }
        __syncthreads();
    }

    float psum[4][4], psq[4][4];
    #pragma unroll
    for (int m = 0; m < 4; ++m)
        #pragma unroll
        for (int rr = 0; rr < 4; ++rr) { psum[m][rr] = 0.f; psq[m][rr] = 0.f; }
    #pragma unroll
    for (int m = 0; m < 4; ++m)
        #pragma unroll
        for (int n = 0; n < 4; ++n) {
            int col = w * 64 + n * 16 + l15;
            float bb = s_b3[col];
            #pragma unroll
            for (int rr = 0; rr < 4; ++rr) {
                float xv = acc[m][n][rr] + bb;
                acc[m][n][rr] = xv;
                psum[m][rr] += xv;
                psq[m][rr] += xv * xv;
            }
        }
    #pragma unroll
    for (int m = 0; m < 4; ++m)
        #pragma unroll
        for (int rr = 0; rr < 4; ++rr) {
            float s = psum[m][rr], q = psq[m][rr];
            s += __shfl_xor(s, 1); s += __shfl_xor(s, 2); s += __shfl_xor(s, 4); s += __shfl_xor(s, 8);
            q += __shfl_xor(q, 1); q += __shfl_xor(q, 2); q += __shfl_xor(q, 4); q += __shfl_xor(q, 8);
            psum[m][rr] = s; psq[m][rr] = q;
        }
    float vs = 0.f, vq = 0.f;
    #pragma unroll
    for (int m = 0; m < 4; ++m)
        #pragma unroll
        for (int rr = 0; rr < 4; ++rr) {
            bool sel = (l15 == m * 4 + rr);
            vs = sel ? psum[m][rr] : vs;
            vq = sel ? psq[m][rr] : vq;
        }
    float (*s_part)[64][2] = (float(*)[64][2])(void*)M_lds;
    {
        int row = (l15 >> 2) * 16 + 4 * g + (l15 & 3);
        s_part[w][row][0] = vs;
        s_part[w][row][1] = vq;
    }
    __syncthreads();
    if (tid < 64) {
        float s = s_part[0][tid][0] + s_part[1][tid][0] + s_part[2][tid][0] + s_part[3][tid][0];
        float q = s_part[0][tid][1] + s_part[1][tid][1] + s_part[2][tid][1] + s_part[3][tid][1];
        float mean = s * (1.f / 256.f);
        float var = q * (1.f / 256.f) - mean * mean;
        s_mr[tid][0] = mean;
        s_mr[tid][1] = rsqrtf(var + 1e-5f);
    }
    __syncthreads();

    #pragma unroll
    for (int m = 0; m < 4; ++m)
        #pragma unroll
        for (int rr = 0; rr < 4; ++rr) {
            int row = m * 16 + 4 * g + rr;
            float mean = s_mr[row][0], rstd = s_mr[row][1];
            #pragma unroll
            for (int n = 0; n < 4; ++n) {
                int col = w * 64 + n * 16 + l15;
                float y = (acc[m][n][rr] - mean) * rstd * s_g2[col] + s_be2[col];
                float sy = y * (1.f / (1.f + __expf(-y)));
                M_lds[row * 256 + (col ^ ((row & 7) << 3))] = f2bf(sy);
            }
        }
    __syncthreads();

    // ---- GEMM4: m[64x256] @ W4 (N=128), W4 frags lazy from global; no barriers ----
    f32x4 acc4[4][2] = {};
    for (int kt = 0; kt < 4; ++kt) {
        #pragma unroll
        for (int kk = 0; kk < 2; ++kk) {
            int keB = kk * 32 + 8 * g;
            int keA = kt * 64 + keB;
            bf16x8 af[4], bfr[2];
            #pragma unroll
            for (int m = 0; m < 4; ++m) {
                int rr_ = m * 16 + l15;
                af[m] = *(const bf16x8*)(const void*)&M_lds[rr_ * 256 + (keA ^ ((rr_ & 7) << 3))];
            }
            #pragma unroll
            for (int n2 = 0; n2 < 2; ++n2) {
                int cn = w * 32 + n2 * 16 + l15;
                bfr[n2] = *(const bf16x8*)(const void*)&Wt4[(size_t)cn * 256 + kt * 64 + keB];
            }
            #pragma unroll
            for (int m = 0; m < 4; ++m)
                #pragma unroll
                for (int n2 = 0; n2 < 2; ++n2)
                    acc4[m][n2] = __builtin_amdgcn_mfma_f32_16x16x32_bf16(af[m], bfr[n2], acc4[m][n2], 0, 0, 0);
        }
    }

    #pragma unroll
    for (int m = 0; m < 4; ++m)
        #pragma unroll
        for (int rr = 0; rr < 4; ++rr) {
            int row = m * 16 + 4 * g + rr;
            int nd = r0 + row;
            if (nd < NNODES) {
                #pragma unroll
                for (int n2 = 0; n2 < 2; ++n2) {
                    int col = w * 32 + n2 * 16 + l15;
                    out[(size_t)nd * NF + col] = h[(size_t)nd * NF + col] + acc4[m][n2][rr] + s_b4[col];
                }
            }
        }
}

extern "C" void kernel_launch(void* const* d_in, const int* in_sizes, int n_in,
                              void* d_out, int out_size, void* d_ws, size_t ws_size,
                              hipStream_t stream) {
    const float* h   = (const float*)d_in[0];
    const int* ei    = (const int*)d_in[1];
    const float* W1  = (const float*)d_in[2];
    const float* b1  = (const float*)d_in[3];
    const float* g1  = (const float*)d_in[4];
    const float* be1 = (const float*)d_in[5];
    const float* W2  = (const float*)d_in[6];
    const float* b2  = (const float*)d_in[7];
    const float* W3  = (const float*)d_in[8];
    const float* b3  = (const float*)d_in[9];
    const float* g2  = (const float*)d_in[10];
    const float* be2 = (const float*)d_in[11];
    const float* W4  = (const float*)d_in[12];
    const float* b4  = (const float*)d_in[13];
    float* out = (float*)d_out;

    char* ws = (char*)d_ws;
    float* agg            = (float*)(ws);                      // 51,200,000 B [edge->node]
    // cnt/basep/cursor overlay agg: live only [hist -> scatter], agg memset after
    int* cnt              = (int*)(ws);                        // 200,000 B
    int* basep            = (int*)(ws + 200000);               // 200,000 B
    int* cursor           = (int*)(ws + 400000);               // 200,000 B
    unsigned short* P     = (unsigned short*)(ws + 51200000);  // 25,600,000 B [pq->edge]
    unsigned short* Q     = (unsigned short*)d_out;            // 25,600,000 B [pq->edge], dead before node writes out
    unsigned short* ssrc  = (unsigned short*)(ws + 76800000);  // 1,600,000 B
    unsigned short* sdst  = (unsigned short*)(ws + 78400000);  // 1,600,000 B
    unsigned short* Wtpq  = (unsigned short*)(ws + 80000000);  // 131,072 B
    unsigned short* Wt2   = (unsigned short*)(ws + 80131072);  // 131,072 B
    unsigned short* Wt3   = (unsigned short*)(ws + 80262144);  // 196,608 B
    unsigned short* Wt4   = (unsigned short*)(ws + 80458752);  // 65,536 B  (end ~80.5 MB)

    hipMemsetAsync(ws, 0, 600000, stream);  // zero cnt/basep/cursor

    wpq_kernel<<<(512 * 128 + 255) / 256, 256, 0, stream>>>(W1, Wtpq);
    tcvt_kernel<<<(256 * 256 + 255) / 256, 256, 0, stream>>>(W2, Wt2, 256, 256);
    tcvt_kernel<<<(384 * 256 + 255) / 256, 256, 0, stream>>>(W3, Wt3, 384, 256);
    tcvt_kernel<<<(256 * 128 + 255) / 256, 256, 0, stream>>>(W4, Wt4, 256, 128);

    hist_kernel<<<(NEDGES + 255) / 256, 256, 0, stream>>>(ei, cnt);
    scan_kernel<<<1, 1024, 0, stream>>>(cnt, basep, NNODES);
    scatter_kernel<<<(NEDGES + 255) / 256, 256, 0, stream>>>(ei, basep, cursor, ssrc, sdst);

    pq_kernel<<<(NNODES + 63) / 64, 256, 0, stream>>>(h, Wtpq, b1, P, Q);

    hipMemsetAsync(agg, 0, (size_t)NNODES * NH * sizeof(float), stream);  // cnt region dead now

    edge_kernel<<<NEDGES / 64, 256, 0, stream>>>(P, Q, ssrc, sdst, Wt2, g1, be1, b2, agg);
    node_kernel<<<(NNODES + 63) / 64, 256, 0, stream>>>(h, agg, Wt3, Wt4, b3, g2, be2, b4, out);
}

// Round 15
// 552.164 us; speedup vs baseline: 1.0269x; 1.0002x over previous
//
#include <hip/hip_runtime.h>
#include <hip/hip_bf16.h>
#include <stdint.h>

#define NNODES 50000
#define NEDGES 800000
#define NF 128
#define NH 256

typedef __attribute__((ext_vector_type(8))) __bf16 bf16x8;
typedef __attribute__((ext_vector_type(8))) unsigned short u16x8;
typedef __attribute__((ext_vector_type(4))) float f32x4;

__device__ __forceinline__ unsigned short f2bf(float f) {
    union { float f; unsigned int u; } v; v.f = f;
    unsigned int r = v.u + 0x7fffu + ((v.u >> 16) & 1u);
    return (unsigned short)(r >> 16);
}

// packed f32x2 -> bf16x2 (RNE on gfx950; refcheck-proven r13/r14: absmax identical to f2bf)
__device__ __forceinline__ unsigned int cvtpk(float lo, float hi) {
    unsigned int r;
    asm volatile("v_cvt_pk_bf16_f32 %0, %1, %2" : "=v"(r) : "v"(lo), "v"(hi));
    return r;
}

__device__ __forceinline__ void gload16(const void* g, void* l) {
    __builtin_amdgcn_global_load_lds(
        (const __attribute__((address_space(1))) void*)g,
        (__attribute__((address_space(3))) void*)l,
        16, 0, 0);
}

// W [K][Nn] f32 row-major -> Wt [Nn][K] bf16
__global__ __launch_bounds__(256) void tcvt_kernel(const float* __restrict__ W,
                                                   unsigned short* __restrict__ Wt, int K, int Nn) {
    int i = blockIdx.x * 256 + threadIdx.x;
    if (i < K * Nn) {
        int k = i / Nn, n = i - k * Nn;
        Wt[n * K + k] = f2bf(W[i]);
    }
}

// W1 [256][256] f32 -> Wtpq [512][128] bf16 : n<256 -> W1a col n; n>=256 -> W1b col n-256
__global__ __launch_bounds__(256) void wpq_kernel(const float* __restrict__ W1,
                                                  unsigned short* __restrict__ Wtpq) {
    int i = blockIdx.x * 256 + threadIdx.x;
    if (i < 512 * 128) {
        int n = i >> 7, k = i & 127;
        float v = (n < 256) ? W1[k * 256 + n] : W1[(128 + k) * 256 + (n - 256)];
        Wtpq[i] = f2bf(v);
    }
}

// ---------------- sort-by-row kernels ----------------
__global__ __launch_bounds__(256) void hist_kernel(const int* __restrict__ row, int* __restrict__ cnt) {
    int e = blockIdx.x * 256 + threadIdx.x;
    if (e < NEDGES) atomicAdd(&cnt[row[e]], 1);
}

__global__ __launch_bounds__(1024) void scan_kernel(const int* __restrict__ cnt, int* __restrict__ base, int n) {
    __shared__ int wsum[16];
    __shared__ int s_carry;
    const int tid = threadIdx.x;
    const int lane = tid & 63;
    const int wv = tid >> 6;
    if (tid == 0) s_carry = 0;
    __syncthreads();
    for (int off = 0; off < n; off += 1024) {
        int v = (off + tid < n) ? cnt[off + tid] : 0;
        int acc = v;
        #pragma unroll
        for (int s = 1; s < 64; s <<= 1) {
            int t = __shfl_up(acc, s);
            if (lane >= s) acc += t;
        }
        if (lane == 63) wsum[wv] = acc;
        __syncthreads();
        if (wv == 0) {
            int x = (lane < 16) ? wsum[lane] : 0;
            #pragma unroll
            for (int s = 1; s < 16; s <<= 1) {
                int t = __shfl_up(x, s);
                if (lane >= s) x += t;
            }
            if (lane < 16) wsum[lane] = x;
        }
        __syncthreads();
        int c = s_carry;
        int wtot = __shfl(acc, 63);
        int woff = wsum[wv] - wtot;
        if (off + tid < n) base[off + tid] = c + woff + acc - v;
        __syncthreads();
        if (tid == 0) s_carry = c + wsum[15];
        __syncthreads();
    }
}

__global__ __launch_bounds__(256) void scatter_kernel(const int* __restrict__ ei,
                                                      const int* __restrict__ base,
                                                      int* __restrict__ cursor,
                                                      unsigned short* __restrict__ ssrc,
                                                      unsigned short* __restrict__ sdst) {
    int e = blockIdx.x * 256 + threadIdx.x;
    if (e < NEDGES) {
        int r = ei[e];
        int c = ei[NEDGES + e];
        int pos = base[r] + atomicAdd(&cursor[r], 1);
        ssrc[pos] = (unsigned short)r;
        sdst[pos] = (unsigned short)c;
    }
}

// ---------------- P/Q precompute ----------------
// P = h@W1a + b1, Q = h@W1b  (both [NNODES][256] bf16). BM=64, K=128, 4 waves.
__global__ __launch_bounds__(256, 2)
void pq_kernel(const float* __restrict__ h,
               const unsigned short* __restrict__ Wtpq,
               const float* __restrict__ b1,
               unsigned short* __restrict__ P,
               unsigned short* __restrict__ Q)
{
    __shared__ __align__(16) unsigned short A_lds[64 * 128];
    const int tid = threadIdx.x;
    const int lane = tid & 63;
    const int w = tid >> 6;
    const int l15 = lane & 15;
    const int g = lane >> 4;
    const int r0 = blockIdx.x * 64;

    float b1r[4];
    #pragma unroll
    for (int n = 0; n < 4; ++n) b1r[n] = b1[w * 64 + n * 16 + l15];

    // reg-stage A (h f32 -> bf16, swizzled chunks)
    #pragma unroll
    for (int i = 0; i < 4; ++i) {
        int idx = i * 256 + tid;
        int row = idx >> 4, cl = idx & 15;
        int nd = r0 + row; if (nd >= NNODES) nd = NNODES - 1;
        const float* sp = h + (size_t)nd * NF + ((cl ^ (row & 7)) * 8);
        float4 va = *(const float4*)sp;
        float4 vb = *(const float4*)(sp + 4);
        u16x8 mv;
        mv[0] = f2bf(va.x); mv[1] = f2bf(va.y); mv[2] = f2bf(va.z); mv[3] = f2bf(va.w);
        mv[4] = f2bf(vb.x); mv[5] = f2bf(vb.y); mv[6] = f2bf(vb.z); mv[7] = f2bf(vb.w);
        *(u16x8*)(void*)&A_lds[row * 128 + cl * 8] = mv;
    }
    __syncthreads();

    #pragma unroll
    for (int p = 0; p < 2; ++p) {
        bf16x8 Bf[4][4];
        #pragma unroll
        for (int n = 0; n < 4; ++n) {
            int cn = w * 64 + n * 16 + l15;
            #pragma unroll
            for (int ks = 0; ks < 4; ++ks)
                Bf[n][ks] = *(const bf16x8*)(const void*)&Wtpq[(size_t)(p * 256 + cn) * 128 + ks * 32 + 8 * g];
        }
        f32x4 acc[4][4] = {};
        #pragma unroll
        for (int ks = 0; ks < 4; ++ks) {
            bf16x8 af[4];
            #pragma unroll
            for (int m = 0; m < 4; ++m) {
                int r = m * 16 + l15;
                af[m] = *(const bf16x8*)(const void*)&A_lds[r * 128 + ((ks * 32 + 8 * g) ^ ((r & 7) << 3))];
            }
            #pragma unroll
            for (int m = 0; m < 4; ++m)
                #pragma unroll
                for (int n = 0; n < 4; ++n)
                    acc[m][n] = __builtin_amdgcn_mfma_f32_16x16x32_bf16(af[m], Bf[n][ks], acc[m][n], 0, 0, 0);
        }
        unsigned short* dst = p ? Q : P;
        #pragma unroll
        for (int m = 0; m < 4; ++m)
            #pragma unroll
            for (int rr = 0; rr < 4; ++rr) {
                int row = m * 16 + 4 * g + rr;
                int nd = r0 + row;
                if (nd < NNODES) {
                    #pragma unroll
                    for (int n = 0; n < 4; ++n) {
                        int col = w * 64 + n * 16 + l15;
                        float v = acc[m][n][rr] + (p ? 0.f : b1r[n]);
                        dst[(size_t)nd * NH + col] = f2bf(v);
                    }
                }
            }
    }
}

// ---------------- edge kernel ----------------
// r12 register shape + cvtpk with PAIRWISE-IMMEDIATE consumption (2 floats live,
// not 8). Stats accumulate in identical k-order (value-identical to r12/r14).
__global__ __launch_bounds__(256, 3)
void edge_kernel(const unsigned short* __restrict__ P,
                 const unsigned short* __restrict__ Q,
                 const unsigned short* __restrict__ ssrc,
                 const unsigned short* __restrict__ sdst,
                 const unsigned short* __restrict__ Wt2,
                 const float* __restrict__ g1, const float* __restrict__ be1,
                 const float* __restrict__ b2,
                 float* __restrict__ agg)
{
    // union region: M bf16 64x256 (B1..B4) | S f32 32x260 half-tile (post-B4)
    __shared__ __align__(16) char smem[33280];
    unsigned short* M_lds = (unsigned short*)smem;
    float* S = (float*)smem;
    __shared__ float s_part[4][64][2];
    __shared__ unsigned short s_src[64];
    __shared__ __align__(16) float s_g1[256], s_be1[256];

    const int tid = threadIdx.x;
    const int lane = tid & 63;
    const int w = tid >> 6;
    const int l15 = lane & 15;
    const int g = lane >> 4;
    const int e0 = blockIdx.x * 64;
    const int r = lane;  // thread's row (edge slot); wave w owns cols [w*64, w*64+64)

    s_g1[tid] = g1[tid]; s_be1[tid] = be1[tid];
    if (tid < 64) s_src[tid] = ssrc[e0 + tid];

    // ---- gather x = P[src] + Q[tgt]; stats on exact f32; pairwise cvtpk pack ----
    int nds = ssrc[e0 + r];
    int ndt = sdst[e0 + r];
    const bf16x8* Pp = (const bf16x8*)(const void*)(P + (size_t)nds * NH + w * 64);
    const bf16x8* Qp = (const bf16x8*)(const void*)(Q + (size_t)ndt * NH + w * 64);

    uint4 xb[8];
    float sum = 0.f, sq = 0.f;
    #pragma unroll
    for (int j = 0; j < 8; ++j) {
        bf16x8 pv = Pp[j];
        bf16x8 qv = Qp[j];
        unsigned int w0, w1, w2, w3;
        {
            float a = (float)pv[0] + (float)qv[0];
            float b = (float)pv[1] + (float)qv[1];
            sum += a; sq += a * a; sum += b; sq += b * b;
            w0 = cvtpk(a, b);
        }
        {
            float a = (float)pv[2] + (float)qv[2];
            float b = (float)pv[3] + (float)qv[3];
            sum += a; sq += a * a; sum += b; sq += b * b;
            w1 = cvtpk(a, b);
        }
        {
            float a = (float)pv[4] + (float)qv[4];
            float b = (float)pv[5] + (float)qv[5];
            sum += a; sq += a * a; sum += b; sq += b * b;
            w2 = cvtpk(a, b);
        }
        {
            float a = (float)pv[6] + (float)qv[6];
            float b = (float)pv[7] + (float)qv[7];
            sum += a; sq += a * a; sum += b; sq += b * b;
            w3 = cvtpk(a, b);
        }
        xb[j].x = w0; xb[j].y = w1; xb[j].z = w2; xb[j].w = w3;
    }
    s_part[w][r][0] = sum;
    s_part[w][r][1] = sq;
    __syncthreads();                                   // B1: partials visible

    // ---- all-thread LN finalize (each thread reduces its own row) ----
    float mean, rstd;
    {
        float s = s_part[0][r][0] + s_part[1][r][0] + s_part[2][r][0] + s_part[3][r][0];
        float q = s_part[0][r][1] + s_part[1][r][1] + s_part[2][r][1] + s_part[3][r][1];
        mean = s * (1.f / 256.f);
        float var = q * (1.f / 256.f) - mean * mean;
        rstd = rsqrtf(var + 1e-5f);
    }

    // ---- LN apply + SiLU -> M tile (pairwise: float2 gamma/beta, immediate cvtpk) ----
    {
        #pragma unroll
        for (int j = 0; j < 8; ++j) {
            bf16x8 xv = *(bf16x8*)(void*)&xb[j];
            unsigned int mw[4];
            #pragma unroll
            for (int kk = 0; kk < 4; ++kk) {
                float2 ga = *(const float2*)&s_g1[w * 64 + j * 8 + 2 * kk];
                float2 bb = *(const float2*)&s_be1[w * 64 + j * 8 + 2 * kk];
                float xa = (float)xv[2 * kk];
                float xbv = (float)xv[2 * kk + 1];
                float ya = (xa - mean) * rstd * ga.x + bb.x;
                float yb = (xbv - mean) * rstd * ga.y + bb.y;
                float sa = ya * (1.f / (1.f + __expf(-ya)));
                float sb = yb * (1.f / (1.f + __expf(-yb)));
                mw[kk] = cvtpk(sa, sb);
            }
            uint4 mv;
            mv.x = mw[0]; mv.y = mw[1]; mv.z = mw[2]; mv.w = mw[3];
            *(uint4*)(void*)&M_lds[r * 256 + w * 64 + ((j ^ (r & 7)) * 8)] = mv;
        }
    }
    __syncthreads();                                   // B3: M ready (xb dead)

    // ---- GEMM2: m[64x256] @ W2, W2 frags loaded per-ks (short live range) ----
    f32x4 acc2[4][4] = {};
    #pragma unroll
    for (int ks = 0; ks < 8; ++ks) {
        bf16x8 bfr[4];
        #pragma unroll
        for (int n = 0; n < 4; ++n) {
            int cn = w * 64 + n * 16 + l15;
            bfr[n] = *(const bf16x8*)(const void*)&Wt2[cn * 256 + ks * 32 + 8 * g];
        }
        bf16x8 af[4];
        #pragma unroll
        for (int m = 0; m < 4; ++m) {
            int rr_ = m * 16 + l15;
            af[m] = *(const bf16x8*)(const void*)&M_lds[rr_ * 256 + ((ks * 32 + 8 * g) ^ ((rr_ & 7) << 3))];
        }
        #pragma unroll
        for (int m = 0; m < 4; ++m)
            #pragma unroll
            for (int n = 0; n < 4; ++n)
                acc2[m][n] = __builtin_amdgcn_mfma_f32_16x16x32_bf16(af[m], bfr[n], acc2[m][n], 0, 0, 0);
    }
    __syncthreads();                                   // B4: M reads done, S may overlay

    // ---- split epilogue: two 32-row S half-tiles; batched 8-wide run-reduce ----
    {
        float b2r[4];
        #pragma unroll
        for (int n = 0; n < 4; ++n) b2r[n] = b2[w * 64 + n * 16 + l15];

        const int col = tid;
        float run = 0.f;
        int prev = s_src[0];
        #pragma unroll
        for (int p = 0; p < 2; ++p) {
            #pragma unroll
            for (int mm = 0; mm < 2; ++mm) {
                int m = 2 * p + mm;
                #pragma unroll
                for (int rr = 0; rr < 4; ++rr) {
                    int lrow = mm * 16 + 4 * g + rr;   // local row in half-tile
                    #pragma unroll
                    for (int n = 0; n < 4; ++n) {
                        int c2 = w * 64 + n * 16 + l15;
                        S[lrow * 260 + c2] = acc2[m][n][rr] + b2r[n];
                    }
                }
            }
            __syncthreads();                           // S half ready
            #pragma unroll 1
            for (int c8 = 0; c8 < 4; ++c8) {
                float v[8];
                int nd8[8];
                #pragma unroll
                for (int u = 0; u < 8; ++u) v[u] = S[(c8 * 8 + u) * 260 + col];
                #pragma unroll
                for (int u = 0; u < 8; ++u) nd8[u] = s_src[32 * p + c8 * 8 + u];
                #pragma unroll
                for (int u = 0; u < 8; ++u) {
                    if (nd8[u] != prev) {
                        atomicAdd(&agg[(size_t)prev * NH + col], run);
                        run = 0.f;
                        prev = nd8[u];
                    }
                    run += v[u];
                }
            }
            if (p == 0) __syncthreads();               // protect S before overwrite
        }
        atomicAdd(&agg[(size_t)prev * NH + col], run);
    }
}

// ---------------- node kernel ----------------
// Lazy W3/W4 fragments from global (L2-hot) — B_lds deleted; LDS ~45 KB -> 3 blocks/CU.
__global__ __launch_bounds__(256, 3)
void node_kernel(const float* __restrict__ h,
                 const float* __restrict__ agg,
                 const unsigned short* __restrict__ Wt3,
                 const unsigned short* __restrict__ Wt4,
                 const float* __restrict__ b3, const float* __restrict__ g2,
                 const float* __restrict__ be2, const float* __restrict__ b4,
                 float* __restrict__ out)
{
    __shared__ __align__(16) unsigned short A_lds[64 * 64];
    __shared__ __align__(16) unsigned short M_lds[64 * 256];
    __shared__ float s_mr[64][2];
    __shared__ float s_b3[256], s_g2[256], s_be2[256], s_b4[128];

    const int tid = threadIdx.x;
    const int lane = tid & 63;
    const int w = tid >> 6;
    const int l15 = lane & 15;
    const int g = lane >> 4;
    const int r0 = blockIdx.x * 64;

    s_b3[tid] = b3[tid]; s_g2[tid] = g2[tid]; s_be2[tid] = be2[tid];
    if (tid < 128) s_b4[tid] = b4[tid];
    __syncthreads();

    f32x4 acc[4][4] = {};

    for (int kt = 0; kt < 6; ++kt) {
        // A reg-stage (f32 -> bf16, swizzled chunks)
        #pragma unroll
        for (int i = 0; i < 2; ++i) {
            int idx = i * 256 + tid;
            int row = idx >> 3, cl = idx & 7;
            int nd = r0 + row; if (nd >= NNODES) nd = NNODES - 1;
            int scol = (cl ^ (row & 7)) * 8;
            const float* sp = (kt < 2) ? (h + (size_t)nd * NF + kt * 64 + scol)
                                       : (agg + (size_t)nd * NH + (kt - 2) * 64 + scol);
            float4 va = *(const float4*)sp;
            float4 vb = *(const float4*)(sp + 4);
            u16x8 mv;
            mv[0] = f2bf(va.x); mv[1] = f2bf(va.y); mv[2] = f2bf(va.z); mv[3] = f2bf(va.w);
            mv[4] = f2bf(vb.x); mv[5] = f2bf(vb.y); mv[6] = f2bf(vb.z); mv[7] = f2bf(vb.w);
            *(u16x8*)(void*)&A_lds[row * 64 + cl * 8] = mv;
        }
        __syncthreads();
        #pragma unroll
        for (int kk = 0; kk < 2; ++kk) {
            int ke = kk * 32 + 8 * g;
            bf16x8 af[4], bfr[4];
            #pragma unroll
            for (int m = 0; m < 4; ++m) {
                int rr_ = m * 16 + l15;
                af[m] = *(const bf16x8*)(const void*)&A_lds[rr_ * 64 + (ke ^ ((rr_ & 7) << 3))];
            }
            #pragma unroll
            for (int n = 0; n < 4; ++n) {
                int cn = w * 64 + n * 16 + l15;
                bfr[n] = *(const bf16x8*)(const void*)&Wt3[(size_t)cn * 384 + kt * 64 + ke];
            }
            #pragma unroll
            for (int m = 0; m < 4; ++m)
                #pragma unroll
                for (int n = 0; n < 4; ++n)
                    acc[m][n] = __builtin_amdgcn_mfma_f32_16x16x32_bf16(af[m], bfr[n], acc[m][n], 0, 0, 0);
        }
        __syncthreads();
    }

    float psum[4][4], psq[4][4];
    #pragma unroll
    for (int m = 0; m < 4; ++m)
        #pragma unroll
        for (int rr = 0; rr < 4; ++rr) { psum[m][rr] = 0.f; psq[m][rr] = 0.f; }
    #pragma unroll
    for (int m = 0; m < 4; ++m)
        #pragma unroll
        for (int n = 0; n < 4; ++n) {
            int col = w * 64 + n * 16 + l15;
            float bb = s_b3[col];
            #pragma unroll
            for (int rr = 0; rr < 4; ++rr) {
                float xv = acc[m][n][rr] + bb;
                acc[m][n][rr] = xv;
                psum[m][rr] += xv;
                psq[m][rr] += xv * xv;
            }
        }
    #pragma unroll
    for (int m = 0; m < 4; ++m)
        #pragma unroll
        for (int rr = 0; rr < 4; ++rr) {
            float s = psum[m][rr], q = psq[m][rr];
            s += __shfl_xor(s, 1); s += __shfl_xor(s, 2); s += __shfl_xor(s, 4); s += __shfl_xor(s, 8);
            q += __shfl_xor(q, 1); q += __shfl_xor(q, 2); q += __shfl_xor(q, 4); q += __shfl_xor(q, 8);
            psum[m][rr] = s; psq[m][rr] = q;
        }
    float vs = 0.f, vq = 0.f;
    #pragma unroll
    for (int m = 0; m < 4; ++m)
        #pragma unroll
        for (int rr = 0; rr < 4; ++rr) {
            bool sel = (l15 == m * 4 + rr);
            vs = sel ? psum[m][rr] : vs;
            vq = sel ? psq[m][rr] : vq;
        }
    float (*s_part)[64][2] = (float(*)[64][2])(void*)M_lds;
    {
        int row = (l15 >> 2) * 16 + 4 * g + (l15 & 3);
        s_part[w][row][0] = vs;
        s_part[w][row][1] = vq;
    }
    __syncthreads();
    if (tid < 64) {
        float s = s_part[0][tid][0] + s_part[1][tid][0] + s_part[2][tid][0] + s_part[3][tid][0];
        float q = s_part[0][tid][1] + s_part[1][tid][1] + s_part[2][tid][1] + s_part[3][tid][1];
        float mean = s * (1.f / 256.f);
        float var = q * (1.f / 256.f) - mean * mean;
        s_mr[tid][0] = mean;
        s_mr[tid][1] = rsqrtf(var + 1e-5f);
    }
    __syncthreads();

    #pragma unroll
    for (int m = 0; m < 4; ++m)
        #pragma unroll
        for (int rr = 0; rr < 4; ++rr) {
            int row = m * 16 + 4 * g + rr;
            float mean = s_mr[row][0], rstd = s_mr[row][1];
            #pragma unroll
            for (int n = 0; n < 4; ++n) {
                int col = w * 64 + n * 16 + l15;
                float y = (acc[m][n][rr] - mean) * rstd * s_g2[col] + s_be2[col];
                float sy = y * (1.f / (1.f + __expf(-y)));
                M_lds[row * 256 + (col ^ ((row & 7) << 3))] = f2bf(sy);
            }
        }
    __syncthreads();

    // ---- GEMM4: m[64x256] @ W4 (N=128), W4 frags lazy from global; no barriers ----
    f32x4 acc4[4][2] = {};
    for (int kt = 0; kt < 4; ++kt) {
        #pragma unroll
        for (int kk = 0; kk < 2; ++kk) {
            int keB = kk * 32 + 8 * g;
            int keA = kt * 64 + keB;
            bf16x8 af[4], bfr[2];
            #pragma unroll
            for (int m = 0; m < 4; ++m) {
                int rr_ = m * 16 + l15;
                af[m] = *(const bf16x8*)(const void*)&M_lds[rr_ * 256 + (keA ^ ((rr_ & 7) << 3))];
            }
            #pragma unroll
            for (int n2 = 0; n2 < 2; ++n2) {
                int cn = w * 32 + n2 * 16 + l15;
                bfr[n2] = *(const bf16x8*)(const void*)&Wt4[(size_t)cn * 256 + kt * 64 + keB];
            }
            #pragma unroll
            for (int m = 0; m < 4; ++m)
                #pragma unroll
                for (int n2 = 0; n2 < 2; ++n2)
                    acc4[m][n2] = __builtin_amdgcn_mfma_f32_16x16x32_bf16(af[m], bfr[n2], acc4[m][n2], 0, 0, 0);
        }
    }

    #pragma unroll
    for (int m = 0; m < 4; ++m)
        #pragma unroll
        for (int rr = 0; rr < 4; ++rr) {
            int row = m * 16 + 4 * g + rr;
            int nd = r0 + row;
            if (nd < NNODES) {
                #pragma unroll
                for (int n2 = 0; n2 < 2; ++n2) {
                    int col = w * 32 + n2 * 16 + l15;
                    out[(size_t)nd * NF + col] = h[(size_t)nd * NF + col] + acc4[m][n2][rr] + s_b4[col];
                }
            }
        }
}

extern "C" void kernel_launch(void* const* d_in, const int* in_sizes, int n_in,
                              void* d_out, int out_size, void* d_ws, size_t ws_size,
                              hipStream_t stream) {
    const float* h   = (const float*)d_in[0];
    const int* ei    = (const int*)d_in[1];
    const float* W1  = (const float*)d_in[2];
    const float* b1  = (const float*)d_in[3];
    const float* g1  = (const float*)d_in[4];
    const float* be1 = (const float*)d_in[5];
    const float* W2  = (const float*)d_in[6];
    const float* b2  = (const float*)d_in[7];
    const float* W3  = (const float*)d_in[8];
    const float* b3  = (const float*)d_in[9];
    const float* g2  = (const float*)d_in[10];
    const float* be2 = (const float*)d_in[11];
    const float* W4  = (const float*)d_in[12];
    const float* b4  = (const float*)d_in[13];
    float* out = (float*)d_out;

    char* ws = (char*)d_ws;
    float* agg            = (float*)(ws);                      // 51,200,000 B [edge->node]
    // cnt/basep/cursor overlay agg: live only [hist -> scatter], agg memset after
    int* cnt              = (int*)(ws);                        // 200,000 B
    int* basep            = (int*)(ws + 200000);               // 200,000 B
    int* cursor           = (int*)(ws + 400000);               // 200,000 B
    unsigned short* P     = (unsigned short*)(ws + 51200000);  // 25,600,000 B [pq->edge]
    unsigned short* Q     = (unsigned short*)d_out;            // 25,600,000 B [pq->edge], dead before node writes out
    unsigned short* ssrc  = (unsigned short*)(ws + 76800000);  // 1,600,000 B
    unsigned short* sdst  = (unsigned short*)(ws + 78400000);  // 1,600,000 B
    unsigned short* Wtpq  = (unsigned short*)(ws + 80000000);  // 131,072 B
    unsigned short* Wt2   = (unsigned short*)(ws + 80131072);  // 131,072 B
    unsigned short* Wt3   = (unsigned short*)(ws + 80262144);  // 196,608 B
    unsigned short* Wt4   = (unsigned short*)(ws + 80458752);  // 65,536 B  (end ~80.5 MB)

    hipMemsetAsync(ws, 0, 600000, stream);  // zero cnt/basep/cursor

    wpq_kernel<<<(512 * 128 + 255) / 256, 256, 0, stream>>>(W1, Wtpq);
    tcvt_kernel<<<(256 * 256 + 255) / 256, 256, 0, stream>>>(W2, Wt2, 256, 256);
    tcvt_kernel<<<(384 * 256 + 255) / 256, 256, 0, stream>>>(W3, Wt3, 384, 256);
    tcvt_kernel<<<(256 * 128 + 255) / 256, 256, 0, stream>>>(W4, Wt4, 256, 128);

    hist_kernel<<<(NEDGES + 255) / 256, 256, 0, stream>>>(ei, cnt);
    scan_kernel<<<1, 1024, 0, stream>>>(cnt, basep, NNODES);
    scatter_kernel<<<(NEDGES + 255) / 256, 256, 0, stream>>>(ei, basep, cursor, ssrc, sdst);

    pq_kernel<<<(NNODES + 63) / 64, 256, 0, stream>>>(h, Wtpq, b1, P, Q);

    hipMemsetAsync(agg, 0, (size_t)NNODES * NH * sizeof(float), stream);  // cnt region dead now

    edge_kernel<<<NEDGES / 64, 256, 0, stream>>>(P, Q, ssrc, sdst, Wt2, g1, be1, b2, agg);
    node_kernel<<<(NNODES + 63) / 64, 256, 0, stream>>>(h, agg, Wt3, Wt4, b3, g2, be2, b4, out);
}

// Round 16
// 530.539 us; speedup vs baseline: 1.0688x; 1.0408x over previous
//
#include <hip/hip_runtime.h>
#include <hip/hip_bf16.h>
#include <stdint.h>

#define NNODES 50000
#define NEDGES 800000
#define NF 128
#define NH 256

typedef __attribute__((ext_vector_type(8))) __bf16 bf16x8;
typedef __attribute__((ext_vector_type(8))) unsigned short u16x8;
typedef __attribute__((ext_vector_type(4))) float f32x4;

__device__ __forceinline__ unsigned short f2bf(float f) {
    union { float f; unsigned int u; } v; v.f = f;
    unsigned int r = v.u + 0x7fffu + ((v.u >> 16) & 1u);
    return (unsigned short)(r >> 16);
}

__device__ __forceinline__ void gload16(const void* g, void* l) {
    __builtin_amdgcn_global_load_lds(
        (const __attribute__((address_space(1))) void*)g,
        (__attribute__((address_space(3))) void*)l,
        16, 0, 0);
}

// W [K][Nn] f32 row-major -> Wt [Nn][K] bf16
__global__ __launch_bounds__(256) void tcvt_kernel(const float* __restrict__ W,
                                                   unsigned short* __restrict__ Wt, int K, int Nn) {
    int i = blockIdx.x * 256 + threadIdx.x;
    if (i < K * Nn) {
        int k = i / Nn, n = i - k * Nn;
        Wt[n * K + k] = f2bf(W[i]);
    }
}

// W1 [256][256] f32 -> Wtpq [512][128] bf16 : n<256 -> W1a col n; n>=256 -> W1b col n-256
__global__ __launch_bounds__(256) void wpq_kernel(const float* __restrict__ W1,
                                                  unsigned short* __restrict__ Wtpq) {
    int i = blockIdx.x * 256 + threadIdx.x;
    if (i < 512 * 128) {
        int n = i >> 7, k = i & 127;
        float v = (n < 256) ? W1[k * 256 + n] : W1[(128 + k) * 256 + (n - 256)];
        Wtpq[i] = f2bf(v);
    }
}

// ---------------- sort-by-row kernels ----------------
__global__ __launch_bounds__(256) void hist_kernel(const int* __restrict__ row, int* __restrict__ cnt) {
    int e = blockIdx.x * 256 + threadIdx.x;
    if (e < NEDGES) atomicAdd(&cnt[row[e]], 1);
}

__global__ __launch_bounds__(1024) void scan_kernel(const int* __restrict__ cnt, int* __restrict__ base, int n) {
    __shared__ int wsum[16];
    __shared__ int s_carry;
    const int tid = threadIdx.x;
    const int lane = tid & 63;
    const int wv = tid >> 6;
    if (tid == 0) s_carry = 0;
    __syncthreads();
    for (int off = 0; off < n; off += 1024) {
        int v = (off + tid < n) ? cnt[off + tid] : 0;
        int acc = v;
        #pragma unroll
        for (int s = 1; s < 64; s <<= 1) {
            int t = __shfl_up(acc, s);
            if (lane >= s) acc += t;
        }
        if (lane == 63) wsum[wv] = acc;
        __syncthreads();
        if (wv == 0) {
            int x = (lane < 16) ? wsum[lane] : 0;
            #pragma unroll
            for (int s = 1; s < 16; s <<= 1) {
                int t = __shfl_up(x, s);
                if (lane >= s) x += t;
            }
            if (lane < 16) wsum[lane] = x;
        }
        __syncthreads();
        int c = s_carry;
        int wtot = __shfl(acc, 63);
        int woff = wsum[wv] - wtot;
        if (off + tid < n) base[off + tid] = c + woff + acc - v;
        __syncthreads();
        if (tid == 0) s_carry = c + wsum[15];
        __syncthreads();
    }
}

__global__ __launch_bounds__(256) void scatter_kernel(const int* __restrict__ ei,
                                                      const int* __restrict__ base,
                                                      int* __restrict__ cursor,
                                                      unsigned short* __restrict__ ssrc,
                                                      unsigned short* __restrict__ sdst) {
    int e = blockIdx.x * 256 + threadIdx.x;
    if (e < NEDGES) {
        int r = ei[e];
        int c = ei[NEDGES + e];
        int pos = base[r] + atomicAdd(&cursor[r], 1);
        ssrc[pos] = (unsigned short)r;
        sdst[pos] = (unsigned short)c;
    }
}

// ---------------- P/Q precompute ----------------
// P = h@W1a + b1, Q = h@W1b  (both [NNODES][256] bf16). BM=64, K=128, 4 waves.
__global__ __launch_bounds__(256, 2)
void pq_kernel(const float* __restrict__ h,
               const unsigned short* __restrict__ Wtpq,
               const float* __restrict__ b1,
               unsigned short* __restrict__ P,
               unsigned short* __restrict__ Q)
{
    __shared__ __align__(16) unsigned short A_lds[64 * 128];
    const int tid = threadIdx.x;
    const int lane = tid & 63;
    const int w = tid >> 6;
    const int l15 = lane & 15;
    const int g = lane >> 4;
    const int r0 = blockIdx.x * 64;

    float b1r[4];
    #pragma unroll
    for (int n = 0; n < 4; ++n) b1r[n] = b1[w * 64 + n * 16 + l15];

    // reg-stage A (h f32 -> bf16, swizzled chunks)
    #pragma unroll
    for (int i = 0; i < 4; ++i) {
        int idx = i * 256 + tid;
        int row = idx >> 4, cl = idx & 15;
        int nd = r0 + row; if (nd >= NNODES) nd = NNODES - 1;
        const float* sp = h + (size_t)nd * NF + ((cl ^ (row & 7)) * 8);
        float4 va = *(const float4*)sp;
        float4 vb = *(const float4*)(sp + 4);
        u16x8 mv;
        mv[0] = f2bf(va.x); mv[1] = f2bf(va.y); mv[2] = f2bf(va.z); mv[3] = f2bf(va.w);
        mv[4] = f2bf(vb.x); mv[5] = f2bf(vb.y); mv[6] = f2bf(vb.z); mv[7] = f2bf(vb.w);
        *(u16x8*)(void*)&A_lds[row * 128 + cl * 8] = mv;
    }
    __syncthreads();

    #pragma unroll
    for (int p = 0; p < 2; ++p) {
        bf16x8 Bf[4][4];
        #pragma unroll
        for (int n = 0; n < 4; ++n) {
            int cn = w * 64 + n * 16 + l15;
            #pragma unroll
            for (int ks = 0; ks < 4; ++ks)
                Bf[n][ks] = *(const bf16x8*)(const void*)&Wtpq[(size_t)(p * 256 + cn) * 128 + ks * 32 + 8 * g];
        }
        f32x4 acc[4][4] = {};
        #pragma unroll
        for (int ks = 0; ks < 4; ++ks) {
            bf16x8 af[4];
            #pragma unroll
            for (int m = 0; m < 4; ++m) {
                int r = m * 16 + l15;
                af[m] = *(const bf16x8*)(const void*)&A_lds[r * 128 + ((ks * 32 + 8 * g) ^ ((r & 7) << 3))];
            }
            #pragma unroll
            for (int m = 0; m < 4; ++m)
                #pragma unroll
                for (int n = 0; n < 4; ++n)
                    acc[m][n] = __builtin_amdgcn_mfma_f32_16x16x32_bf16(af[m], Bf[n][ks], acc[m][n], 0, 0, 0);
        }
        unsigned short* dst = p ? Q : P;
        #pragma unroll
        for (int m = 0; m < 4; ++m)
            #pragma unroll
            for (int rr = 0; rr < 4; ++rr) {
                int row = m * 16 + 4 * g + rr;
                int nd = r0 + row;
                if (nd < NNODES) {
                    #pragma unroll
                    for (int n = 0; n < 4; ++n) {
                        int col = w * 64 + n * 16 + l15;
                        float v = acc[m][n][rr] + (p ? 0.f : b1r[n]);
                        dst[(size_t)nd * NH + col] = f2bf(v);
                    }
                }
            }
    }
}

// ---------------- edge kernel ----------------
// r12-proven optimum: xb packed bf16 (f2bf), all-thread LN finalize, W2 lazy
// per-ks, split S epilogue. VGPR 64 + 64 AGPR = 128 -> 4 waves/SIMD at (256,3).
__global__ __launch_bounds__(256, 3)
void edge_kernel(const unsigned short* __restrict__ P,
                 const unsigned short* __restrict__ Q,
                 const unsigned short* __restrict__ ssrc,
                 const unsigned short* __restrict__ sdst,
                 const unsigned short* __restrict__ Wt2,
                 const float* __restrict__ g1, const float* __restrict__ be1,
                 const float* __restrict__ b2,
                 float* __restrict__ agg)
{
    // union region: M bf16 64x256 (B1..B4) | S f32 32x260 half-tile (post-B4)
    __shared__ __align__(16) char smem[33280];
    unsigned short* M_lds = (unsigned short*)smem;
    float* S = (float*)smem;
    __shared__ float s_part[4][64][2];
    __shared__ unsigned short s_src[64];
    __shared__ __align__(16) float s_g1[256], s_be1[256];

    const int tid = threadIdx.x;
    const int lane = tid & 63;
    const int w = tid >> 6;
    const int l15 = lane & 15;
    const int g = lane >> 4;
    const int e0 = blockIdx.x * 64;
    const int r = lane;  // thread's row (edge slot); wave w owns cols [w*64, w*64+64)

    s_g1[tid] = g1[tid]; s_be1[tid] = be1[tid];
    if (tid < 64) s_src[tid] = ssrc[e0 + tid];

    // ---- gather x = P[src] + Q[tgt]; stats on exact f32; store packed bf16 ----
    int nds = ssrc[e0 + r];
    int ndt = sdst[e0 + r];
    const bf16x8* Pp = (const bf16x8*)(const void*)(P + (size_t)nds * NH + w * 64);
    const bf16x8* Qp = (const bf16x8*)(const void*)(Q + (size_t)ndt * NH + w * 64);

    u16x8 xb[8];
    float sum = 0.f, sq = 0.f;
    #pragma unroll
    for (int j = 0; j < 8; ++j) {
        bf16x8 pv = Pp[j];
        bf16x8 qv = Qp[j];
        u16x8 mv;
        #pragma unroll
        for (int k = 0; k < 8; ++k) {
            float xx = (float)pv[k] + (float)qv[k];
            sum += xx;
            sq += xx * xx;
            mv[k] = f2bf(xx);
        }
        xb[j] = mv;
    }
    s_part[w][r][0] = sum;
    s_part[w][r][1] = sq;
    __syncthreads();                                   // B1: partials visible

    // ---- all-thread LN finalize: each thread reduces its own row (r = lane) ----
    float mean, rstd;
    {
        float s = s_part[0][r][0] + s_part[1][r][0] + s_part[2][r][0] + s_part[3][r][0];
        float q = s_part[0][r][1] + s_part[1][r][1] + s_part[2][r][1] + s_part[3][r][1];
        mean = s * (1.f / 256.f);
        float var = q * (1.f / 256.f) - mean * mean;
        rstd = rsqrtf(var + 1e-5f);
    }

    // ---- LN apply + SiLU -> M tile (bf16, swizzled b128 chunk writes) ----
    {
        #pragma unroll
        for (int j = 0; j < 8; ++j) {
            bf16x8 xv = *(bf16x8*)(void*)&xb[j];
            float ga[8], bb[8];
            *(float4*)&ga[0] = *(const float4*)&s_g1[w * 64 + j * 8];
            *(float4*)&ga[4] = *(const float4*)&s_g1[w * 64 + j * 8 + 4];
            *(float4*)&bb[0] = *(const float4*)&s_be1[w * 64 + j * 8];
            *(float4*)&bb[4] = *(const float4*)&s_be1[w * 64 + j * 8 + 4];
            u16x8 mv;
            #pragma unroll
            for (int k = 0; k < 8; ++k) {
                float xx = (float)xv[k];
                float y = (xx - mean) * rstd * ga[k] + bb[k];
                float sy = y * (1.f / (1.f + __expf(-y)));
                mv[k] = f2bf(sy);
            }
            *(u16x8*)(void*)&M_lds[r * 256 + w * 64 + ((j ^ (r & 7)) * 8)] = mv;
        }
    }
    __syncthreads();                                   // B3: M ready (xb dead)

    // ---- GEMM2: m[64x256] @ W2, W2 frags loaded per-ks (short live range) ----
    f32x4 acc2[4][4] = {};
    #pragma unroll
    for (int ks = 0; ks < 8; ++ks) {
        bf16x8 bfr[4];
        #pragma unroll
        for (int n = 0; n < 4; ++n) {
            int cn = w * 64 + n * 16 + l15;
            bfr[n] = *(const bf16x8*)(const void*)&Wt2[cn * 256 + ks * 32 + 8 * g];
        }
        bf16x8 af[4];
        #pragma unroll
        for (int m = 0; m < 4; ++m) {
            int rr_ = m * 16 + l15;
            af[m] = *(const bf16x8*)(const void*)&M_lds[rr_ * 256 + ((ks * 32 + 8 * g) ^ ((rr_ & 7) << 3))];
        }
        #pragma unroll
        for (int m = 0; m < 4; ++m)
            #pragma unroll
            for (int n = 0; n < 4; ++n)
                acc2[m][n] = __builtin_amdgcn_mfma_f32_16x16x32_bf16(af[m], bfr[n], acc2[m][n], 0, 0, 0);
    }
    __syncthreads();                                   // B4: M reads done, S may overlay

    // ---- split epilogue: two 32-row S half-tiles + run-reduce (run/prev in regs) ----
    {
        float b2r[4];
        #pragma unroll
        for (int n = 0; n < 4; ++n) b2r[n] = b2[w * 64 + n * 16 + l15];

        const int col = tid;
        float run = 0.f;
        int prev = s_src[0];
        #pragma unroll
        for (int p = 0; p < 2; ++p) {
            #pragma unroll
            for (int mm = 0; mm < 2; ++mm) {
                int m = 2 * p + mm;
                #pragma unroll
                for (int rr = 0; rr < 4; ++rr) {
                    int lrow = mm * 16 + 4 * g + rr;   // local row in half-tile
                    #pragma unroll
                    for (int n = 0; n < 4; ++n) {
                        int c2 = w * 64 + n * 16 + l15;
                        S[lrow * 260 + c2] = acc2[m][n][rr] + b2r[n];
                    }
                }
            }
            __syncthreads();                           // S half ready
            #pragma unroll 1
            for (int rr = 0; rr < 32; ++rr) {
                int nd = s_src[32 * p + rr];
                if (nd != prev) {
                    atomicAdd(&agg[(size_t)prev * NH + col], run);
                    run = 0.f;
                    prev = nd;
                }
                run += S[rr * 260 + col];
            }
            if (p == 0) __syncthreads();               // protect S before overwrite
        }
        atomicAdd(&agg[(size_t)prev * NH + col], run);
    }
}

// ---------------- node kernel ----------------
// Lazy W3/W4 fragments from global (L2-hot) — B_lds deleted; LDS ~45 KB -> 3 blocks/CU.
__global__ __launch_bounds__(256, 3)
void node_kernel(const float* __restrict__ h,
                 const float* __restrict__ agg,
                 const unsigned short* __restrict__ Wt3,
                 const unsigned short* __restrict__ Wt4,
                 const float* __restrict__ b3, const float* __restrict__ g2,
                 const float* __restrict__ be2, const float* __restrict__ b4,
                 float* __restrict__ out)
{
    __shared__ __align__(16) unsigned short A_lds[64 * 64];
    __shared__ __align__(16) unsigned short M_lds[64 * 256];
    __shared__ float s_mr[64][2];
    __shared__ float s_b3[256], s_g2[256], s_be2[256], s_b4[128];

    const int tid = threadIdx.x;
    const int lane = tid & 63;
    const int w = tid >> 6;
    const int l15 = lane & 15;
    const int g = lane >> 4;
    const int r0 = blockIdx.x * 64;

    s_b3[tid] = b3[tid]; s_g2[tid] = g2[tid]; s_be2[tid] = be2[tid];
    if (tid < 128) s_b4[tid] = b4[tid];
    __syncthreads();

    f32x4 acc[4][4] = {};

    for (int kt = 0; kt < 6; ++kt) {
        // A reg-stage (f32 -> bf16, swizzled chunks)
        #pragma unroll
        for (int i = 0; i < 2; ++i) {
            int idx = i * 256 + tid;
            int row = idx >> 3, cl = idx & 7;
            int nd = r0 + row; if (nd >= NNODES) nd = NNODES - 1;
            int scol = (cl ^ (row & 7)) * 8;
            const float* sp = (kt < 2) ? (h + (size_t)nd * NF + kt * 64 + scol)
                                       : (agg + (size_t)nd * NH + (kt - 2) * 64 + scol);
            float4 va = *(const float4*)sp;
            float4 vb = *(const float4*)(sp + 4);
            u16x8 mv;
            mv[0] = f2bf(va.x); mv[1] = f2bf(va.y); mv[2] = f2bf(va.z); mv[3] = f2bf(va.w);
            mv[4] = f2bf(vb.x); mv[5] = f2bf(vb.y); mv[6] = f2bf(vb.z); mv[7] = f2bf(vb.w);
            *(u16x8*)(void*)&A_lds[row * 64 + cl * 8] = mv;
        }
        __syncthreads();
        #pragma unroll
        for (int kk = 0; kk < 2; ++kk) {
            int ke = kk * 32 + 8 * g;
            bf16x8 af[4], bfr[4];
            #pragma unroll
            for (int m = 0; m < 4; ++m) {
                int rr_ = m * 16 + l15;
                af[m] = *(const bf16x8*)(const void*)&A_lds[rr_ * 64 + (ke ^ ((rr_ & 7) << 3))];
            }
            #pragma unroll
            for (int n = 0; n < 4; ++n) {
                int cn = w * 64 + n * 16 + l15;
                bfr[n] = *(const bf16x8*)(const void*)&Wt3[(size_t)cn * 384 + kt * 64 + ke];
            }
            #pragma unroll
            for (int m = 0; m < 4; ++m)
                #pragma unroll
                for (int n = 0; n < 4; ++n)
                    acc[m][n] = __builtin_amdgcn_mfma_f32_16x16x32_bf16(af[m], bfr[n], acc[m][n], 0, 0, 0);
        }
        __syncthreads();
    }

    float psum[4][4], psq[4][4];
    #pragma unroll
    for (int m = 0; m < 4; ++m)
        #pragma unroll
        for (int rr = 0; rr < 4; ++rr) { psum[m][rr] = 0.f; psq[m][rr] = 0.f; }
    #pragma unroll
    for (int m = 0; m < 4; ++m)
        #pragma unroll
        for (int n = 0; n < 4; ++n) {
            int col = w * 64 + n * 16 + l15;
            float bb = s_b3[col];
            #pragma unroll
            for (int rr = 0; rr < 4; ++rr) {
                float xv = acc[m][n][rr] + bb;
                acc[m][n][rr] = xv;
                psum[m][rr] += xv;
                psq[m][rr] += xv * xv;
            }
        }
    #pragma unroll
    for (int m = 0; m < 4; ++m)
        #pragma unroll
        for (int rr = 0; rr < 4; ++rr) {
            float s = psum[m][rr], q = psq[m][rr];
            s += __shfl_xor(s, 1); s += __shfl_xor(s, 2); s += __shfl_xor(s, 4); s += __shfl_xor(s, 8);
            q += __shfl_xor(q, 1); q += __shfl_xor(q, 2); q += __shfl_xor(q, 4); q += __shfl_xor(q, 8);
            psum[m][rr] = s; psq[m][rr] = q;
        }
    float vs = 0.f, vq = 0.f;
    #pragma unroll
    for (int m = 0; m < 4; ++m)
        #pragma unroll
        for (int rr = 0; rr < 4; ++rr) {
            bool sel = (l15 == m * 4 + rr);
            vs = sel ? psum[m][rr] : vs;
            vq = sel ? psq[m][rr] : vq;
        }
    float (*s_part)[64][2] = (float(*)[64][2])(void*)M_lds;
    {
        int row = (l15 >> 2) * 16 + 4 * g + (l15 & 3);
        s_part[w][row][0] = vs;
        s_part[w][row][1] = vq;
    }
    __syncthreads();
    if (tid < 64) {
        float s = s_part[0][tid][0] + s_part[1][tid][0] + s_part[2][tid][0] + s_part[3][tid][0];
        float q = s_part[0][tid][1] + s_part[1][tid][1] + s_part[2][tid][1] + s_part[3][tid][1];
        float mean = s * (1.f / 256.f);
        float var = q * (1.f / 256.f) - mean * mean;
        s_mr[tid][0] = mean;
        s_mr[tid][1] = rsqrtf(var + 1e-5f);
    }
    __syncthreads();

    #pragma unroll
    for (int m = 0; m < 4; ++m)
        #pragma unroll
        for (int rr = 0; rr < 4; ++rr) {
            int row = m * 16 + 4 * g + rr;
            float mean = s_mr[row][0], rstd = s_mr[row][1];
            #pragma unroll
            for (int n = 0; n < 4; ++n) {
                int col = w * 64 + n * 16 + l15;
                float y = (acc[m][n][rr] - mean) * rstd * s_g2[col] + s_be2[col];
                float sy = y * (1.f / (1.f + __expf(-y)));
                M_lds[row * 256 + (col ^ ((row & 7) << 3))] = f2bf(sy);
            }
        }
    __syncthreads();

    // ---- GEMM4: m[64x256] @ W4 (N=128), W4 frags lazy from global; no barriers ----
    f32x4 acc4[4][2] = {};
    for (int kt = 0; kt < 4; ++kt) {
        #pragma unroll
        for (int kk = 0; kk < 2; ++kk) {
            int keB = kk * 32 + 8 * g;
            int keA = kt * 64 + keB;
            bf16x8 af[4], bfr[2];
            #pragma unroll
            for (int m = 0; m < 4; ++m) {
                int rr_ = m * 16 + l15;
                af[m] = *(const bf16x8*)(const void*)&M_lds[rr_ * 256 + (keA ^ ((rr_ & 7) << 3))];
            }
            #pragma unroll
            for (int n2 = 0; n2 < 2; ++n2) {
                int cn = w * 32 + n2 * 16 + l15;
                bfr[n2] = *(const bf16x8*)(const void*)&Wt4[(size_t)cn * 256 + kt * 64 + keB];
            }
            #pragma unroll
            for (int m = 0; m < 4; ++m)
                #pragma unroll
                for (int n2 = 0; n2 < 2; ++n2)
                    acc4[m][n2] = __builtin_amdgcn_mfma_f32_16x16x32_bf16(af[m], bfr[n2], acc4[m][n2], 0, 0, 0);
        }
    }

    #pragma unroll
    for (int m = 0; m < 4; ++m)
        #pragma unroll
        for (int rr = 0; rr < 4; ++rr) {
            int row = m * 16 + 4 * g + rr;
            int nd = r0 + row;
            if (nd < NNODES) {
                #pragma unroll
                for (int n2 = 0; n2 < 2; ++n2) {
                    int col = w * 32 + n2 * 16 + l15;
                    out[(size_t)nd * NF + col] = h[(size_t)nd * NF + col] + acc4[m][n2][rr] + s_b4[col];
                }
            }
        }
}

extern "C" void kernel_launch(void* const* d_in, const int* in_sizes, int n_in,
                              void* d_out, int out_size, void* d_ws, size_t ws_size,
                              hipStream_t stream) {
    const float* h   = (const float*)d_in[0];
    const int* ei    = (const int*)d_in[1];
    const float* W1  = (const float*)d_in[2];
    const float* b1  = (const float*)d_in[3];
    const float* g1  = (const float*)d_in[4];
    const float* be1 = (const float*)d_in[5];
    const float* W2  = (const float*)d_in[6];
    const float* b2  = (const float*)d_in[7];
    const float* W3  = (const float*)d_in[8];
    const float* b3  = (const float*)d_in[9];
    const float* g2  = (const float*)d_in[10];
    const float* be2 = (const float*)d_in[11];
    const float* W4  = (const float*)d_in[12];
    const float* b4  = (const float*)d_in[13];
    float* out = (float*)d_out;

    char* ws = (char*)d_ws;
    float* agg            = (float*)(ws);                      // 51,200,000 B [edge->node]
    // cnt/basep/cursor overlay agg: live only [hist -> scatter], agg memset after
    int* cnt              = (int*)(ws);                        // 200,000 B
    int* basep            = (int*)(ws + 200000);               // 200,000 B
    int* cursor           = (int*)(ws + 400000);               // 200,000 B
    unsigned short* P     = (unsigned short*)(ws + 51200000);  // 25,600,000 B [pq->edge]
    unsigned short* Q     = (unsigned short*)d_out;            // 25,600,000 B [pq->edge], dead before node writes out
    unsigned short* ssrc  = (unsigned short*)(ws + 76800000);  // 1,600,000 B
    unsigned short* sdst  = (unsigned short*)(ws + 78400000);  // 1,600,000 B
    unsigned short* Wtpq  = (unsigned short*)(ws + 80000000);  // 131,072 B
    unsigned short* Wt2   = (unsigned short*)(ws + 80131072);  // 131,072 B
    unsigned short* Wt3   = (unsigned short*)(ws + 80262144);  // 196,608 B
    unsigned short* Wt4   = (unsigned short*)(ws + 80458752);  // 65,536 B  (end ~80.5 MB)

    hipMemsetAsync(ws, 0, 600000, stream);  // zero cnt/basep/cursor

    wpq_kernel<<<(512 * 128 + 255) / 256, 256, 0, stream>>>(W1, Wtpq);
    tcvt_kernel<<<(256 * 256 + 255) / 256, 256, 0, stream>>>(W2, Wt2, 256, 256);
    tcvt_kernel<<<(384 * 256 + 255) / 256, 256, 0, stream>>>(W3, Wt3, 384, 256);
    tcvt_kernel<<<(256 * 128 + 255) / 256, 256, 0, stream>>>(W4, Wt4, 256, 128);

    hist_kernel<<<(NEDGES + 255) / 256, 256, 0, stream>>>(ei, cnt);
    scan_kernel<<<1, 1024, 0, stream>>>(cnt, basep, NNODES);
    scatter_kernel<<<(NEDGES + 255) / 256, 256, 0, stream>>>(ei, basep, cursor, ssrc, sdst);

    pq_kernel<<<(NNODES + 63) / 64, 256, 0, stream>>>(h, Wtpq, b1, P, Q);

    hipMemsetAsync(agg, 0, (size_t)NNODES * NH * sizeof(float), stream);  // cnt region dead now

    edge_kernel<<<NEDGES / 64, 256, 0, stream>>>(P, Q, ssrc, sdst, Wt2, g1, be1, b2, agg);
    node_kernel<<<(NNODES + 63) / 64, 256, 0, stream>>>(h, agg, Wt3, Wt4, b3, g2, be2, b4, out);
}